// Round 2
// baseline (715.457 us; speedup 1.0000x reference)
//
#include <hip/hip_runtime.h>
#include <hip/hip_bf16.h>
#include <stdint.h>

// Problem constants: B=2, S=2048, D=1024, H=16, DH=64
constexpr int TS = 2048;
constexpr int TD = 1024;
constexpr int TH = 16;
constexpr int TM = 4096;        // B*S rows
constexpr float GELU_C = 0.7978845608f;

typedef __hip_bfloat16 bf16;
typedef __attribute__((ext_vector_type(8))) short bf16x8;
typedef __attribute__((ext_vector_type(4))) float f32x4;

__device__ __forceinline__ void gload16(const void* g, void* l) {
  __builtin_amdgcn_global_load_lds(
      (const __attribute__((address_space(1))) void*)g,
      (__attribute__((address_space(3))) void*)l, 16, 0, 0);
}

__device__ __forceinline__ unsigned short f2bfbits(float f) {
  bf16 h = __float2bfloat16(f);
  unsigned short u;
  __builtin_memcpy(&u, &h, 2);
  return u;
}

__device__ __forceinline__ float gelu_f(float x) {
  float x3 = x * x * x;
  return 0.5f * x * (1.0f + tanhf(GELU_C * (x + 0.044715f * x3)));
}

// ---------------- weight convert+transpose: W[K][N] f32 -> Wt[N][K] bf16 ----
__global__ __launch_bounds__(256) void k_transpose_bf16(
    const float* __restrict__ W, bf16* __restrict__ Wt, int K, int N) {
  __shared__ float t[64][65];
  int k0 = blockIdx.x * 64, n0 = blockIdx.y * 64;
  int tid = threadIdx.x;
  int c = tid & 63, r0 = tid >> 6;
#pragma unroll
  for (int i = 0; i < 16; ++i) {
    int r = r0 + i * 4;
    t[r][c] = W[(size_t)(k0 + r) * N + n0 + c];
  }
  __syncthreads();
#pragma unroll
  for (int i = 0; i < 16; ++i) {
    int r = r0 + i * 4;   // row of Wt = n0+r
    Wt[(size_t)(n0 + r) * K + k0 + c] = __float2bfloat16(t[c][r]);
  }
}

// ---------------- LayerNorm (fp32 in, bf16 out), row = 1024 -----------------
__global__ __launch_bounds__(256) void k_layernorm(
    const float* __restrict__ x, const float* __restrict__ gamma,
    const float* __restrict__ beta, bf16* __restrict__ out) {
  int row = blockIdx.x;
  const float* xr = x + (size_t)row * TD;
  int tid = threadIdx.x;
  float4 v = ((const float4*)xr)[tid];
  float s = v.x + v.y + v.z + v.w;
  float ss = v.x * v.x + v.y * v.y + v.z * v.z + v.w * v.w;
#pragma unroll
  for (int off = 32; off; off >>= 1) {
    s += __shfl_down(s, off);
    ss += __shfl_down(ss, off);
  }
  __shared__ float red[8];
  __shared__ float stat[2];
  int wid = tid >> 6, lane = tid & 63;
  if (lane == 0) { red[wid] = s; red[4 + wid] = ss; }
  __syncthreads();
  if (tid == 0) {
    float S1 = red[0] + red[1] + red[2] + red[3];
    float S2 = red[4] + red[5] + red[6] + red[7];
    float mean = S1 / (float)TD;
    float var = (S2 - S1 * mean) / (float)(TD - 1);
    var = fmaxf(var, 0.0f);
    stat[0] = mean;
    stat[1] = 1.0f / (sqrtf(var) + 1e-5f);
  }
  __syncthreads();
  float mean = stat[0], rstd = stat[1];
  float4 g = ((const float4*)gamma)[tid];
  float4 bb = ((const float4*)beta)[tid];
  ushort4 r4;
  r4.x = f2bfbits(g.x * (v.x - mean) * rstd + bb.x);
  r4.y = f2bfbits(g.y * (v.y - mean) * rstd + bb.y);
  r4.z = f2bfbits(g.z * (v.z - mean) * rstd + bb.z);
  r4.w = f2bfbits(g.w * (v.w - mean) * rstd + bb.w);
  ((ushort4*)(out + (size_t)row * TD))[tid] = r4;
}

// ---------------- bf16 MFMA GEMM: C = A[M][K] @ Bt[N][K]^T + epilogue -------
// 128x128 tile, BK=64, 4 waves (2x2), m97 structure + st-swizzled LDS.
// MODE 0: out bf16 = acc + bias
// MODE 1: out f32  = acc + bias + resid
// MODE 2: out bf16 = gelu(acc + bias)
template <int MODE>
__global__ __launch_bounds__(256) void k_gemm(
    const bf16* __restrict__ A, const bf16* __restrict__ Bt,
    const float* __restrict__ bias, const float* __restrict__ resid,
    void* __restrict__ out, int Mm, int Nn, int Kk) {
  __shared__ __align__(1024) char smem[32768];   // sA 16KB | sB 16KB
  char* sA = smem;
  char* sB = smem + 16384;
  int bm = blockIdx.y, bn = blockIdx.x;
  int tid = threadIdx.x, w = tid >> 6, lane = tid & 63;
  int wm = w >> 1, wn = w & 1;
  f32x4 acc[4][4] = {};
  size_t arow0 = (size_t)bm * 128;
  size_t brow0 = (size_t)bn * 128;
  int srow = lane >> 3;                 // row within 8-row chunk
  int sslot = (lane & 7) ^ srow;        // pre-swizzled logical 16B slot (rule #21)
  int nkt = Kk >> 6;
  for (int kt = 0; kt < nkt; ++kt) {
    __syncthreads();
#pragma unroll
    for (int t = 0; t < 4; ++t) {
      int chunk = w * 4 + t;
      int row = chunk * 8 + srow;
      const char* g = (const char*)(A + (arow0 + row) * (size_t)Kk + kt * 64) + sslot * 16;
      gload16(g, sA + chunk * 1024);
    }
#pragma unroll
    for (int t = 0; t < 4; ++t) {
      int chunk = w * 4 + t;
      int row = chunk * 8 + srow;
      const char* g = (const char*)(Bt + (brow0 + row) * (size_t)Kk + kt * 64) + sslot * 16;
      gload16(g, sB + chunk * 1024);
    }
    __syncthreads();
#pragma unroll
    for (int ks = 0; ks < 2; ++ks) {
      bf16x8 af[4], bfr[4];
#pragma unroll
      for (int i = 0; i < 4; ++i) {
        int row = wm * 64 + i * 16 + (lane & 15);
        int off = row * 128 + ((ks * 64 + (lane >> 4) * 16) ^ ((row & 7) << 4));
        af[i] = *(const bf16x8*)(sA + off);
      }
#pragma unroll
      for (int j = 0; j < 4; ++j) {
        int row = wn * 64 + j * 16 + (lane & 15);
        int off = row * 128 + ((ks * 64 + (lane >> 4) * 16) ^ ((row & 7) << 4));
        bfr[j] = *(const bf16x8*)(sB + off);
      }
#pragma unroll
      for (int i = 0; i < 4; ++i)
#pragma unroll
        for (int j = 0; j < 4; ++j)
          acc[i][j] = __builtin_amdgcn_mfma_f32_16x16x32_bf16(af[i], bfr[j], acc[i][j], 0, 0, 0);
    }
  }
  int rbase = (lane >> 4) * 4;
  int cbase = lane & 15;
#pragma unroll
  for (int i = 0; i < 4; ++i) {
#pragma unroll
    for (int j = 0; j < 4; ++j) {
      int n = bn * 128 + wn * 64 + j * 16 + cbase;
      float bv = bias[n];
#pragma unroll
      for (int r = 0; r < 4; ++r) {
        int m = bm * 128 + wm * 64 + i * 16 + rbase + r;
        float vv = acc[i][j][r] + bv;
        size_t idx = (size_t)m * Nn + n;
        if constexpr (MODE == 0) {
          ((bf16*)out)[idx] = __float2bfloat16(vv);
        } else if constexpr (MODE == 1) {
          ((float*)out)[idx] = vv + resid[idx];
        } else {
          ((bf16*)out)[idx] = __float2bfloat16(gelu_f(vv));
        }
      }
    }
  }
}

// ---------------- flash attention (causal), bf16 MFMA -----------------------
// qkv: bf16 [B*S][3072] with per-head layout h*192 + {0:q,64:k,128:v} + dh
// o:   bf16 [B*S][1024] (h*64 + dh)
__global__ __launch_bounds__(256) void k_attn(
    const bf16* __restrict__ qkv, bf16* __restrict__ outp) {
  int bh = blockIdx.y;
  int b = bh >> 4, h = bh & 15;
  int qb = blockIdx.x * 64;
  int tid = threadIdx.x, w = tid >> 6, lane = tid & 63;
  __shared__ __align__(1024) char sK[8192];    // [64 k][64 dh] bf16, swizzled
  __shared__ __align__(1024) char sVt[8192];   // [64 dh][64 k] bf16, swizzled
  __shared__ __align__(1024) char sP[4][2048]; // per-wave [16 q][64 k] bf16, swizzled
  const bf16* qkv_b = qkv + (size_t)b * TS * 3072 + h * 192;
  const unsigned short* qkv_u = (const unsigned short*)qkv_b;

  int q0 = qb + w * 16;
  int mrow = lane & 15;   // A-operand row / D col
  int kgrp = lane >> 4;   // 0..3

  // Q fragments (A layout: m=lane&15, k=kgrp*8+j), dh slices 0-31 / 32-63
  const bf16* qrow = qkv_b + (size_t)(q0 + mrow) * 3072;
  bf16x8 qf[2];
  qf[0] = *(const bf16x8*)(qrow + kgrp * 8);
  qf[1] = *(const bf16x8*)(qrow + 32 + kgrp * 8);

  float m_st[4] = {-1e30f, -1e30f, -1e30f, -1e30f};
  float l_st[4] = {0.f, 0.f, 0.f, 0.f};
  f32x4 oacc[4] = {};

  int nkt = blockIdx.x + 1;
  for (int kt = 0; kt < nkt; ++kt) {
    __syncthreads();
    {   // stage K tile: sK[r][dh], byte = r*128 + ((dh*2)^((r&7)<<4))
      int dh2 = (tid & 31) * 2;
      int rr0 = tid >> 5;
#pragma unroll
      for (int p = 0; p < 8; ++p) {
        int r = rr0 + p * 8;
        uint32_t val = *(const uint32_t*)(qkv_u + (size_t)(kt * 64 + r) * 3072 + 64 + dh2);
        *(uint32_t*)(sK + r * 128 + ((dh2 * 2) ^ ((r & 7) << 4))) = val;
      }
      // stage V transposed: sVt[dh][kr], byte = dh*128 + ((kr*2)^((dh&7)<<4))
      int dh = tid & 63;
      int kp0 = tid >> 6;
#pragma unroll
      for (int p = 0; p < 8; ++p) {
        int kr = (kp0 + p * 4) * 2;
        uint32_t va = qkv_u[(size_t)(kt * 64 + kr) * 3072 + 128 + dh];
        uint32_t vb = qkv_u[(size_t)(kt * 64 + kr + 1) * 3072 + 128 + dh];
        uint32_t val = va | (vb << 16);
        *(uint32_t*)(sVt + dh * 128 + ((kr * 2) ^ ((dh & 7) << 4))) = val;
      }
    }
    __syncthreads();
    if (kt * 64 <= q0 + 15) {
      // ---- QK^T ----
      f32x4 sacc[4] = {};
#pragma unroll
      for (int ks = 0; ks < 2; ++ks) {
#pragma unroll
        for (int nt = 0; nt < 4; ++nt) {
          int krow = nt * 16 + mrow;
          int off = krow * 128 + ((ks * 64 + kgrp * 16) ^ ((krow & 7) << 4));
          bf16x8 kf = *(const bf16x8*)(sK + off);
          sacc[nt] = __builtin_amdgcn_mfma_f32_16x16x32_bf16(qf[ks], kf, sacc[nt], 0, 0, 0);
        }
      }
      // ---- online softmax (rows = kgrp*4+reg, cols spread over lane&15) ----
      float fac[4];
      float p[4][4];   // [nt][reg]
#pragma unroll
      for (int reg = 0; reg < 4; ++reg) {
        int qrow_g = q0 + kgrp * 4 + reg;
        float mx = -1e30f;
#pragma unroll
        for (int nt = 0; nt < 4; ++nt) {
          int kcol = kt * 64 + nt * 16 + mrow;
          float sc = sacc[nt][reg] * 0.125f;
          sc = (kcol <= qrow_g) ? sc : -1e30f;
          sacc[nt][reg] = sc;
          mx = fmaxf(mx, sc);
        }
#pragma unroll
        for (int msk = 1; msk < 16; msk <<= 1) mx = fmaxf(mx, __shfl_xor(mx, msk));
        float mo = m_st[reg];
        float mn = fmaxf(mo, mx);
        float f = __expf(mo - mn);
        float ps = 0.f;
#pragma unroll
        for (int nt = 0; nt < 4; ++nt) {
          float pv = __expf(sacc[nt][reg] - mn);
          p[nt][reg] = pv;
          ps += pv;
        }
#pragma unroll
        for (int msk = 1; msk < 16; msk <<= 1) ps += __shfl_xor(ps, msk);
        l_st[reg] = l_st[reg] * f + ps;
        m_st[reg] = mn;
        fac[reg] = f;
      }
      // ---- write P (D-layout) to LDS, re-read in A-layout ----
#pragma unroll
      for (int reg = 0; reg < 4; ++reg) {
#pragma unroll
        for (int nt = 0; nt < 4; ++nt) {
          int qr = kgrp * 4 + reg;
          int col = nt * 16 + mrow;
          *(unsigned short*)(sP[w] + qr * 128 + ((col * 2) ^ ((qr & 7) << 4))) =
              f2bfbits(p[nt][reg]);
        }
      }
      asm volatile("s_waitcnt lgkmcnt(0)" ::: "memory");
      // ---- rescale + PV ----
#pragma unroll
      for (int nt = 0; nt < 4; ++nt)
#pragma unroll
        for (int reg = 0; reg < 4; ++reg) oacc[nt][reg] *= fac[reg];
#pragma unroll
      for (int ks = 0; ks < 2; ++ks) {
        int off = mrow * 128 + ((ks * 64 + kgrp * 16) ^ ((mrow & 7) << 4));
        bf16x8 pf = *(const bf16x8*)(sP[w] + off);
#pragma unroll
        for (int nt = 0; nt < 4; ++nt) {
          int dh = nt * 16 + mrow;
          int voff = dh * 128 + ((ks * 64 + kgrp * 16) ^ ((dh & 7) << 4));
          bf16x8 vf = *(const bf16x8*)(sVt + voff);
          oacc[nt] = __builtin_amdgcn_mfma_f32_16x16x32_bf16(pf, vf, oacc[nt], 0, 0, 0);
        }
      }
    }
  }
  // ---- finalize ----
#pragma unroll
  for (int reg = 0; reg < 4; ++reg) {
    float inv = 1.0f / l_st[reg];
    int qrow_g = q0 + kgrp * 4 + reg;
    bf16* orow = outp + (size_t)(b * TS + qrow_g) * TD + h * 64;
#pragma unroll
    for (int nt = 0; nt < 4; ++nt) {
      int dh = nt * 16 + mrow;
      orow[dh] = __float2bfloat16(oacc[nt][reg] * inv);
    }
  }
}

// ---------------- launch -----------------------------------------------------
extern "C" void kernel_launch(void* const* d_in, const int* in_sizes, int n_in,
                              void* d_out, int out_size, void* d_ws, size_t ws_size,
                              hipStream_t stream) {
  const float* x      = (const float*)d_in[0];
  const float* gamma1 = (const float*)d_in[1];
  const float* beta1  = (const float*)d_in[2];
  const float* W_qkv  = (const float*)d_in[3];
  const float* b_qkv  = (const float*)d_in[4];
  const float* W_o    = (const float*)d_in[5];
  const float* b_o    = (const float*)d_in[6];
  const float* gamma2 = (const float*)d_in[7];
  const float* beta2  = (const float*)d_in[8];
  const float* W_up   = (const float*)d_in[9];
  const float* b_up   = (const float*)d_in[10];
  const float* W_down = (const float*)d_in[11];
  const float* b_down = (const float*)d_in[12];

  char* ws = (char*)d_ws;
  bf16*  wt_qkv  = (bf16*)(ws + 0);                  //  6291456
  bf16*  wt_o    = (bf16*)(ws + 6291456);            //  2097152
  bf16*  wt_up   = (bf16*)(ws + 8388608);            //  8388608
  bf16*  wt_down = (bf16*)(ws + 16777216);           //  8388608
  bf16*  h1      = (bf16*)(ws + 25165824);           //  8388608
  bf16*  qkvb    = (bf16*)(ws + 33554432);           // 25165824
  bf16*  ob      = (bf16*)(ws + 58720256);           //  8388608
  float* attn_o  = (float*)(ws + 67108864);          // 16777216
  bf16*  h2      = (bf16*)(ws + 83886080);           //  8388608
  bf16*  ub      = (bf16*)(ws + 92274688);           // 33554432
  float* outf    = (float*)d_out;

  k_transpose_bf16<<<dim3(16, 48), 256, 0, stream>>>(W_qkv, wt_qkv, 1024, 3072);
  k_transpose_bf16<<<dim3(16, 16), 256, 0, stream>>>(W_o, wt_o, 1024, 1024);
  k_transpose_bf16<<<dim3(16, 64), 256, 0, stream>>>(W_up, wt_up, 1024, 4096);
  k_transpose_bf16<<<dim3(64, 16), 256, 0, stream>>>(W_down, wt_down, 4096, 1024);

  k_layernorm<<<TM, 256, 0, stream>>>(x, gamma1, beta1, h1);
  k_gemm<0><<<dim3(24, 32), 256, 0, stream>>>(h1, wt_qkv, b_qkv, nullptr, qkvb, TM, 3072, 1024);
  k_attn<<<dim3(32, 32), 256, 0, stream>>>(qkvb, ob);
  k_gemm<1><<<dim3(8, 32), 256, 0, stream>>>(ob, wt_o, b_o, x, attn_o, TM, 1024, 1024);
  k_layernorm<<<TM, 256, 0, stream>>>(attn_o, gamma2, beta2, h2);
  k_gemm<2><<<dim3(32, 32), 256, 0, stream>>>(h2, wt_up, b_up, nullptr, ub, TM, 4096, 1024);
  k_gemm<1><<<dim3(8, 32), 256, 0, stream>>>(ub, wt_down, b_down, attn_o, outf, TM, 1024, 4096);
}

// Round 3
// 488.997 us; speedup vs baseline: 1.4631x; 1.4631x over previous
//
#include <hip/hip_runtime.h>
#include <hip/hip_bf16.h>
#include <stdint.h>

// Problem constants: B=2, S=2048, D=1024, H=16, DH=64
constexpr int TS = 2048;
constexpr int TD = 1024;
constexpr int TH = 16;
constexpr int TM = 4096;        // B*S rows
constexpr float GELU_C = 0.7978845608f;

typedef __hip_bfloat16 bf16;
typedef __attribute__((ext_vector_type(8))) short bf16x8;
typedef __attribute__((ext_vector_type(4))) float f32x4;

__device__ __forceinline__ void gload16(const void* g, void* l) {
  __builtin_amdgcn_global_load_lds(
      (const __attribute__((address_space(1))) void*)g,
      (__attribute__((address_space(3))) void*)l, 16, 0, 0);
}

__device__ __forceinline__ unsigned short f2bfbits(float f) {
  bf16 h = __float2bfloat16(f);
  unsigned short u;
  __builtin_memcpy(&u, &h, 2);
  return u;
}

__device__ __forceinline__ float gelu_f(float x) {
  float x3 = x * x * x;
  return 0.5f * x * (1.0f + tanhf(GELU_C * (x + 0.044715f * x3)));
}

// ---------------- weight convert+transpose: W[K][N] f32 -> Wt[N][K] bf16 ----
__global__ __launch_bounds__(256) void k_transpose_bf16(
    const float* __restrict__ W, bf16* __restrict__ Wt, int K, int N) {
  __shared__ float t[64][65];
  int k0 = blockIdx.x * 64, n0 = blockIdx.y * 64;
  int tid = threadIdx.x;
  int c = tid & 63, r0 = tid >> 6;
#pragma unroll
  for (int i = 0; i < 16; ++i) {
    int r = r0 + i * 4;
    t[r][c] = W[(size_t)(k0 + r) * N + n0 + c];
  }
  __syncthreads();
#pragma unroll
  for (int i = 0; i < 16; ++i) {
    int r = r0 + i * 4;   // row of Wt = n0+r
    Wt[(size_t)(n0 + r) * K + k0 + c] = __float2bfloat16(t[c][r]);
  }
}

// ---------------- LayerNorm (fp32 in, bf16 out), row = 1024 -----------------
__global__ __launch_bounds__(256) void k_layernorm(
    const float* __restrict__ x, const float* __restrict__ gamma,
    const float* __restrict__ beta, bf16* __restrict__ out) {
  int row = blockIdx.x;
  const float* xr = x + (size_t)row * TD;
  int tid = threadIdx.x;
  float4 v = ((const float4*)xr)[tid];
  float s = v.x + v.y + v.z + v.w;
  float ss = v.x * v.x + v.y * v.y + v.z * v.z + v.w * v.w;
#pragma unroll
  for (int off = 32; off; off >>= 1) {
    s += __shfl_down(s, off);
    ss += __shfl_down(ss, off);
  }
  __shared__ float red[8];
  __shared__ float stat[2];
  int wid = tid >> 6, lane = tid & 63;
  if (lane == 0) { red[wid] = s; red[4 + wid] = ss; }
  __syncthreads();
  if (tid == 0) {
    float S1 = red[0] + red[1] + red[2] + red[3];
    float S2 = red[4] + red[5] + red[6] + red[7];
    float mean = S1 / (float)TD;
    float var = (S2 - S1 * mean) / (float)(TD - 1);
    var = fmaxf(var, 0.0f);
    stat[0] = mean;
    stat[1] = 1.0f / (sqrtf(var) + 1e-5f);
  }
  __syncthreads();
  float mean = stat[0], rstd = stat[1];
  float4 g = ((const float4*)gamma)[tid];
  float4 bb = ((const float4*)beta)[tid];
  ushort4 r4;
  r4.x = f2bfbits(g.x * (v.x - mean) * rstd + bb.x);
  r4.y = f2bfbits(g.y * (v.y - mean) * rstd + bb.y);
  r4.z = f2bfbits(g.z * (v.z - mean) * rstd + bb.z);
  r4.w = f2bfbits(g.w * (v.w - mean) * rstd + bb.w);
  ((ushort4*)(out + (size_t)row * TD))[tid] = r4;
}

// ---------------- bf16 MFMA GEMM: C = A[M][K] @ Bt[N][K]^T + epilogue -------
// 128x128 tile, BK=64, 4 waves (2x2), m97 structure + st-swizzled LDS.
// MODE 0: out bf16 = acc + bias
// MODE 1: out f32  = acc + bias + resid
// MODE 2: out bf16 = gelu(acc + bias)
template <int MODE>
__global__ __launch_bounds__(256) void k_gemm(
    const bf16* __restrict__ A, const bf16* __restrict__ Bt,
    const float* __restrict__ bias, const float* __restrict__ resid,
    void* __restrict__ out, int Mm, int Nn, int Kk) {
  __shared__ __align__(1024) char smem[32768];   // sA 16KB | sB 16KB
  char* sA = smem;
  char* sB = smem + 16384;
  int bm = blockIdx.y, bn = blockIdx.x;
  int tid = threadIdx.x, w = tid >> 6, lane = tid & 63;
  int wm = w >> 1, wn = w & 1;
  f32x4 acc[4][4] = {};
  size_t arow0 = (size_t)bm * 128;
  size_t brow0 = (size_t)bn * 128;
  int srow = lane >> 3;                 // row within 8-row chunk
  int sslot = (lane & 7) ^ srow;        // pre-swizzled logical 16B slot (rule #21)
  int nkt = Kk >> 6;
  for (int kt = 0; kt < nkt; ++kt) {
    __syncthreads();
#pragma unroll
    for (int t = 0; t < 4; ++t) {
      int chunk = w * 4 + t;
      int row = chunk * 8 + srow;
      const char* g = (const char*)(A + (arow0 + row) * (size_t)Kk + kt * 64) + sslot * 16;
      gload16(g, sA + chunk * 1024);
    }
#pragma unroll
    for (int t = 0; t < 4; ++t) {
      int chunk = w * 4 + t;
      int row = chunk * 8 + srow;
      const char* g = (const char*)(Bt + (brow0 + row) * (size_t)Kk + kt * 64) + sslot * 16;
      gload16(g, sB + chunk * 1024);
    }
    __syncthreads();
#pragma unroll
    for (int ks = 0; ks < 2; ++ks) {
      bf16x8 af[4], bfr[4];
#pragma unroll
      for (int i = 0; i < 4; ++i) {
        int row = wm * 64 + i * 16 + (lane & 15);
        int off = row * 128 + ((ks * 64 + (lane >> 4) * 16) ^ ((row & 7) << 4));
        af[i] = *(const bf16x8*)(sA + off);
      }
#pragma unroll
      for (int j = 0; j < 4; ++j) {
        int row = wn * 64 + j * 16 + (lane & 15);
        int off = row * 128 + ((ks * 64 + (lane >> 4) * 16) ^ ((row & 7) << 4));
        bfr[j] = *(const bf16x8*)(sB + off);
      }
#pragma unroll
      for (int i = 0; i < 4; ++i)
#pragma unroll
        for (int j = 0; j < 4; ++j)
          acc[i][j] = __builtin_amdgcn_mfma_f32_16x16x32_bf16(af[i], bfr[j], acc[i][j], 0, 0, 0);
    }
  }
  int rbase = (lane >> 4) * 4;
  int cbase = lane & 15;
#pragma unroll
  for (int i = 0; i < 4; ++i) {
#pragma unroll
    for (int j = 0; j < 4; ++j) {
      int n = bn * 128 + wn * 64 + j * 16 + cbase;
      float bv = bias[n];
#pragma unroll
      for (int r = 0; r < 4; ++r) {
        int m = bm * 128 + wm * 64 + i * 16 + rbase + r;
        float vv = acc[i][j][r] + bv;
        size_t idx = (size_t)m * Nn + n;
        if constexpr (MODE == 0) {
          ((bf16*)out)[idx] = __float2bfloat16(vv);
        } else if constexpr (MODE == 1) {
          ((float*)out)[idx] = vv + resid[idx];
        } else {
          ((bf16*)out)[idx] = __float2bfloat16(gelu_f(vv));
        }
      }
    }
  }
}

// ---------------- flash attention (causal), bf16 MFMA, balanced + pipelined -
// qkv: bf16 [B*S][3072] with per-head layout h*192 + {0:q,64:k,128:v} + dh
// o:   bf16 [B*S][1024] (h*64 + dh)
// Block j handles q-tile pair (j, 31-j): exactly 33 K-tile iterations per
// block regardless of dispatch->CU mapping. K/V double-buffered; K staged via
// global_load_lds (linear dest + pre-swizzled source), V reg-staged
// (issue-early, write-late).
__global__ __launch_bounds__(256) void k_attn(
    const bf16* __restrict__ qkv, bf16* __restrict__ outp) {
  int bh = blockIdx.x;
  int b = bh >> 4, h = bh & 15;
  int j = blockIdx.y;
  int tid = threadIdx.x, w = tid >> 6, lane = tid & 63;
  __shared__ __align__(1024) char sK[2][8192];    // [64 k][64 dh] bf16, swizzled
  __shared__ __align__(1024) char sVt[2][8192];   // [64 dh][64 k] bf16, swizzled
  __shared__ __align__(1024) char sP[4][2048];    // per-wave [16 q][64 k] bf16
  const unsigned short* qkv_u =
      (const unsigned short*)(qkv + (size_t)b * TS * 3072 + h * 192);

  int mrow = lane & 15;    // A-operand row / D col
  int kgrp = lane >> 4;    // 0..3
  int srowK = lane >> 3;                 // row within 8-row chunk
  int sslotK = (lane & 7) ^ srowK;       // pre-swizzled 16B slot (rule #21)

  uint32_t vr[16];   // V staging registers (2B each, zero-extended)

#pragma unroll 1
  for (int phase = 0; phase < 2; ++phase) {
    int qt = phase ? (31 - j) : j;
    int q0 = qt * 64 + w * 16;
    int nkt = qt + 1;

    // Q fragments (A layout: m=lane&15, k=kgrp*8+jj), dh slices 0-31 / 32-63
    const unsigned short* qrow = qkv_u + (size_t)(q0 + mrow) * 3072;
    bf16x8 qf0 = *(const bf16x8*)(qrow + kgrp * 8);
    bf16x8 qf1 = *(const bf16x8*)(qrow + 32 + kgrp * 8);

    float m_st[4] = {-1e30f, -1e30f, -1e30f, -1e30f};
    float l_st[4] = {0.f, 0.f, 0.f, 0.f};
    f32x4 oacc[4] = {};

    // ---- staging helpers (macros to keep everything in registers) ----
#define STAGE_K(KT, BUF)                                                      \
  {                                                                           \
    _Pragma("unroll")                                                         \
    for (int t = 0; t < 2; ++t) {                                             \
      int chunk = w * 2 + t;                                                  \
      int row = (KT) * 64 + chunk * 8 + srowK;                                \
      const char* g = (const char*)qkv_u + (size_t)row * 6144 + 128 +         \
                      sslotK * 16;                                            \
      gload16(g, sK[BUF] + chunk * 1024);                                     \
    }                                                                         \
  }
#define LOAD_V(KT)                                                            \
  {                                                                           \
    _Pragma("unroll")                                                         \
    for (int p = 0; p < 8; ++p) {                                             \
      int kr = ((KT) * 64) + (w + p * 4) * 2;                                 \
      vr[2 * p]     = qkv_u[(size_t)kr * 3072 + 128 + lane];                  \
      vr[2 * p + 1] = qkv_u[(size_t)(kr + 1) * 3072 + 128 + lane];            \
    }                                                                         \
  }
#define COMMIT_V(BUF)                                                         \
  {                                                                           \
    _Pragma("unroll")                                                         \
    for (int p = 0; p < 8; ++p) {                                             \
      int kr = (w + p * 4) * 2;                                               \
      uint32_t val = vr[2 * p] | (vr[2 * p + 1] << 16);                       \
      *(uint32_t*)(sVt[BUF] + lane * 128 + ((kr * 2) ^ ((lane & 7) << 4))) =  \
          val;                                                                \
    }                                                                         \
  }

    // prologue: stage tile 0 into buffer 0
    STAGE_K(0, 0);
    LOAD_V(0);
    COMMIT_V(0);            // compiler inserts vmcnt wait for vr use
    __syncthreads();        // drains K's global_load_lds + V ds_writes

    for (int kt = 0; kt < nkt; ++kt) {
      int cur = kt & 1;
      int nxt = cur ^ 1;
      if (kt + 1 < nkt) {   // issue next tile's loads before compute (T14)
        STAGE_K(kt + 1, nxt);
        LOAD_V(kt + 1);
      }
      // ---- QK^T ----
      f32x4 sacc[4] = {};
#pragma unroll
      for (int ks = 0; ks < 2; ++ks) {
        bf16x8 qf = ks ? qf1 : qf0;
#pragma unroll
        for (int nt = 0; nt < 4; ++nt) {
          int krow = nt * 16 + mrow;
          int off = krow * 128 + ((ks * 64 + kgrp * 16) ^ ((krow & 7) << 4));
          bf16x8 kf = *(const bf16x8*)(sK[cur] + off);
          sacc[nt] = __builtin_amdgcn_mfma_f32_16x16x32_bf16(qf, kf, sacc[nt], 0, 0, 0);
        }
      }
      // ---- online softmax (rows = kgrp*4+reg, cols spread over lane&15) ----
      float fac[4];
      float p[4][4];   // [nt][reg]
#pragma unroll
      for (int reg = 0; reg < 4; ++reg) {
        int qrow_g = q0 + kgrp * 4 + reg;
        float mx = -1e30f;
#pragma unroll
        for (int nt = 0; nt < 4; ++nt) {
          int kcol = kt * 64 + nt * 16 + mrow;
          float sc = sacc[nt][reg] * 0.125f;
          sc = (kcol <= qrow_g) ? sc : -1e30f;
          sacc[nt][reg] = sc;
          mx = fmaxf(mx, sc);
        }
#pragma unroll
        for (int msk = 1; msk < 16; msk <<= 1) mx = fmaxf(mx, __shfl_xor(mx, msk));
        float mo = m_st[reg];
        float mn = fmaxf(mo, mx);
        float f = __expf(mo - mn);
        float ps = 0.f;
#pragma unroll
        for (int nt = 0; nt < 4; ++nt) {
          float pv = __expf(sacc[nt][reg] - mn);
          p[nt][reg] = pv;
          ps += pv;
        }
#pragma unroll
        for (int msk = 1; msk < 16; msk <<= 1) ps += __shfl_xor(ps, msk);
        l_st[reg] = l_st[reg] * f + ps;
        m_st[reg] = mn;
        fac[reg] = f;
      }
      // ---- write P (D-layout) to per-wave LDS, re-read in A-layout ----
#pragma unroll
      for (int reg = 0; reg < 4; ++reg) {
#pragma unroll
        for (int nt = 0; nt < 4; ++nt) {
          int qr = kgrp * 4 + reg;
          int col = nt * 16 + mrow;
          *(unsigned short*)(sP[w] + qr * 128 + ((col * 2) ^ ((qr & 7) << 4))) =
              f2bfbits(p[nt][reg]);
        }
      }
      asm volatile("s_waitcnt lgkmcnt(0)" ::: "memory");
      __builtin_amdgcn_sched_barrier(0);   // rule #18: pin MFMA below the fence
      // ---- rescale + PV ----
#pragma unroll
      for (int nt = 0; nt < 4; ++nt)
#pragma unroll
        for (int reg = 0; reg < 4; ++reg) oacc[nt][reg] *= fac[reg];
#pragma unroll
      for (int ks = 0; ks < 2; ++ks) {
        int poff = mrow * 128 + ((ks * 64 + kgrp * 16) ^ ((mrow & 7) << 4));
        bf16x8 pf = *(const bf16x8*)(sP[w] + poff);
#pragma unroll
        for (int nt = 0; nt < 4; ++nt) {
          int dh = nt * 16 + mrow;
          int voff = dh * 128 + ((ks * 64 + kgrp * 16) ^ ((dh & 7) << 4));
          bf16x8 vf = *(const bf16x8*)(sVt[cur] + voff);
          oacc[nt] = __builtin_amdgcn_mfma_f32_16x16x32_bf16(pf, vf, oacc[nt], 0, 0, 0);
        }
      }
      if (kt + 1 < nkt) COMMIT_V(nxt);   // write-late (vmcnt wait on vr use)
      __syncthreads();   // single barrier per iteration
    }
    // ---- finalize ----
#pragma unroll
    for (int reg = 0; reg < 4; ++reg) {
      float inv = 1.0f / l_st[reg];
      int qrow_g = q0 + kgrp * 4 + reg;
      bf16* orow = outp + (size_t)(b * TS + qrow_g) * TD + h * 64;
#pragma unroll
      for (int nt = 0; nt < 4; ++nt) {
        int dh = nt * 16 + mrow;
        orow[dh] = __float2bfloat16(oacc[nt][reg] * inv);
      }
    }
#undef STAGE_K
#undef LOAD_V
#undef COMMIT_V
  }
}

// ---------------- launch -----------------------------------------------------
extern "C" void kernel_launch(void* const* d_in, const int* in_sizes, int n_in,
                              void* d_out, int out_size, void* d_ws, size_t ws_size,
                              hipStream_t stream) {
  const float* x      = (const float*)d_in[0];
  const float* gamma1 = (const float*)d_in[1];
  const float* beta1  = (const float*)d_in[2];
  const float* W_qkv  = (const float*)d_in[3];
  const float* b_qkv  = (const float*)d_in[4];
  const float* W_o    = (const float*)d_in[5];
  const float* b_o    = (const float*)d_in[6];
  const float* gamma2 = (const float*)d_in[7];
  const float* beta2  = (const float*)d_in[8];
  const float* W_up   = (const float*)d_in[9];
  const float* b_up   = (const float*)d_in[10];
  const float* W_down = (const float*)d_in[11];
  const float* b_down = (const float*)d_in[12];

  char* ws = (char*)d_ws;
  bf16*  wt_qkv  = (bf16*)(ws + 0);                  //  6291456
  bf16*  wt_o    = (bf16*)(ws + 6291456);            //  2097152
  bf16*  wt_up   = (bf16*)(ws + 8388608);            //  8388608
  bf16*  wt_down = (bf16*)(ws + 16777216);           //  8388608
  bf16*  h1      = (bf16*)(ws + 25165824);           //  8388608
  bf16*  qkvb    = (bf16*)(ws + 33554432);           // 25165824
  bf16*  ob      = (bf16*)(ws + 58720256);           //  8388608
  float* attn_o  = (float*)(ws + 67108864);          // 16777216
  bf16*  h2      = (bf16*)(ws + 83886080);           //  8388608
  bf16*  ub      = (bf16*)(ws + 92274688);           // 33554432
  float* outf    = (float*)d_out;

  k_transpose_bf16<<<dim3(16, 48), 256, 0, stream>>>(W_qkv, wt_qkv, 1024, 3072);
  k_transpose_bf16<<<dim3(16, 16), 256, 0, stream>>>(W_o, wt_o, 1024, 1024);
  k_transpose_bf16<<<dim3(16, 64), 256, 0, stream>>>(W_up, wt_up, 1024, 4096);
  k_transpose_bf16<<<dim3(64, 16), 256, 0, stream>>>(W_down, wt_down, 4096, 1024);

  k_layernorm<<<TM, 256, 0, stream>>>(x, gamma1, beta1, h1);
  k_gemm<0><<<dim3(24, 32), 256, 0, stream>>>(h1, wt_qkv, b_qkv, nullptr, qkvb, TM, 3072, 1024);
  k_attn<<<dim3(64, 16), 256, 0, stream>>>(qkvb, ob);
  k_gemm<1><<<dim3(8, 32), 256, 0, stream>>>(ob, wt_o, b_o, x, attn_o, TM, 1024, 1024);
  k_layernorm<<<TM, 256, 0, stream>>>(attn_o, gamma2, beta2, h2);
  k_gemm<2><<<dim3(32, 32), 256, 0, stream>>>(h2, wt_up, b_up, nullptr, ub, TM, 4096, 1024);
  k_gemm<1><<<dim3(8, 32), 256, 0, stream>>>(ub, wt_down, b_down, attn_o, outf, TM, 1024, 4096);
}

// Round 4
// 488.610 us; speedup vs baseline: 1.4643x; 1.0008x over previous
//
#include <hip/hip_runtime.h>
#include <hip/hip_bf16.h>
#include <stdint.h>

// Problem constants: B=2, S=2048, D=1024, H=16, DH=64
constexpr int TS = 2048;
constexpr int TD = 1024;
constexpr int TM = 4096;        // B*S rows
constexpr float GELU_C = 0.7978845608f;

typedef __hip_bfloat16 bf16;
typedef __attribute__((ext_vector_type(8))) short bf16x8;
typedef __attribute__((ext_vector_type(4))) float f32x4;
typedef __attribute__((ext_vector_type(16))) float f32x16;

__device__ __forceinline__ void gload16(const void* g, void* l) {
  __builtin_amdgcn_global_load_lds(
      (const __attribute__((address_space(1))) void*)g,
      (__attribute__((address_space(3))) void*)l, 16, 0, 0);
}

__device__ __forceinline__ unsigned short f2bfbits(float f) {
  bf16 h = __float2bfloat16(f);
  unsigned short u;
  __builtin_memcpy(&u, &h, 2);
  return u;
}

__device__ __forceinline__ float gelu_f(float x) {
  float x3 = x * x * x;
  return 0.5f * x * (1.0f + tanhf(GELU_C * (x + 0.044715f * x3)));
}

// ---------------- weight convert+transpose: W[K][N] f32 -> Wt[N][K] bf16 ----
__global__ __launch_bounds__(256) void k_transpose_bf16(
    const float* __restrict__ W, bf16* __restrict__ Wt, int K, int N) {
  __shared__ float t[64][65];
  int k0 = blockIdx.x * 64, n0 = blockIdx.y * 64;
  int tid = threadIdx.x;
  int c = tid & 63, r0 = tid >> 6;
#pragma unroll
  for (int i = 0; i < 16; ++i) {
    int r = r0 + i * 4;
    t[r][c] = W[(size_t)(k0 + r) * N + n0 + c];
  }
  __syncthreads();
#pragma unroll
  for (int i = 0; i < 16; ++i) {
    int r = r0 + i * 4;   // row of Wt = n0+r
    Wt[(size_t)(n0 + r) * K + k0 + c] = __float2bfloat16(t[c][r]);
  }
}

// ---------------- LayerNorm (fp32 in, bf16 out), row = 1024 -----------------
__global__ __launch_bounds__(256) void k_layernorm(
    const float* __restrict__ x, const float* __restrict__ gamma,
    const float* __restrict__ beta, bf16* __restrict__ out) {
  int row = blockIdx.x;
  const float* xr = x + (size_t)row * TD;
  int tid = threadIdx.x;
  float4 v = ((const float4*)xr)[tid];
  float s = v.x + v.y + v.z + v.w;
  float ss = v.x * v.x + v.y * v.y + v.z * v.z + v.w * v.w;
#pragma unroll
  for (int off = 32; off; off >>= 1) {
    s += __shfl_down(s, off);
    ss += __shfl_down(ss, off);
  }
  __shared__ float red[8];
  __shared__ float stat[2];
  int wid = tid >> 6, lane = tid & 63;
  if (lane == 0) { red[wid] = s; red[4 + wid] = ss; }
  __syncthreads();
  if (tid == 0) {
    float S1 = red[0] + red[1] + red[2] + red[3];
    float S2 = red[4] + red[5] + red[6] + red[7];
    float mean = S1 / (float)TD;
    float var = (S2 - S1 * mean) / (float)(TD - 1);
    var = fmaxf(var, 0.0f);
    stat[0] = mean;
    stat[1] = 1.0f / (sqrtf(var) + 1e-5f);
  }
  __syncthreads();
  float mean = stat[0], rstd = stat[1];
  float4 g = ((const float4*)gamma)[tid];
  float4 bb = ((const float4*)beta)[tid];
  ushort4 r4;
  r4.x = f2bfbits(g.x * (v.x - mean) * rstd + bb.x);
  r4.y = f2bfbits(g.y * (v.y - mean) * rstd + bb.y);
  r4.z = f2bfbits(g.z * (v.z - mean) * rstd + bb.z);
  r4.w = f2bfbits(g.w * (v.w - mean) * rstd + bb.w);
  ((ushort4*)(out + (size_t)row * TD))[tid] = r4;
}

// ---------------- bf16 MFMA GEMM: C = A[M][K] @ Bt[N][K]^T + epilogue -------
// 128x128 tile, BK=64, 4 waves (2x2), m97 structure + st-swizzled LDS.
template <int MODE>
__global__ __launch_bounds__(256) void k_gemm(
    const bf16* __restrict__ A, const bf16* __restrict__ Bt,
    const float* __restrict__ bias, const float* __restrict__ resid,
    void* __restrict__ out, int Mm, int Nn, int Kk) {
  __shared__ __align__(1024) char smem[32768];   // sA 16KB | sB 16KB
  char* sA = smem;
  char* sB = smem + 16384;
  int bm = blockIdx.y, bn = blockIdx.x;
  int tid = threadIdx.x, w = tid >> 6, lane = tid & 63;
  int wm = w >> 1, wn = w & 1;
  f32x4 acc[4][4] = {};
  size_t arow0 = (size_t)bm * 128;
  size_t brow0 = (size_t)bn * 128;
  int srow = lane >> 3;                 // row within 8-row chunk
  int sslot = (lane & 7) ^ srow;        // pre-swizzled logical 16B slot (rule #21)
  int nkt = Kk >> 6;
  for (int kt = 0; kt < nkt; ++kt) {
    __syncthreads();
#pragma unroll
    for (int t = 0; t < 4; ++t) {
      int chunk = w * 4 + t;
      int row = chunk * 8 + srow;
      const char* g = (const char*)(A + (arow0 + row) * (size_t)Kk + kt * 64) + sslot * 16;
      gload16(g, sA + chunk * 1024);
    }
#pragma unroll
    for (int t = 0; t < 4; ++t) {
      int chunk = w * 4 + t;
      int row = chunk * 8 + srow;
      const char* g = (const char*)(Bt + (brow0 + row) * (size_t)Kk + kt * 64) + sslot * 16;
      gload16(g, sB + chunk * 1024);
    }
    __syncthreads();
#pragma unroll
    for (int ks = 0; ks < 2; ++ks) {
      bf16x8 af[4], bfr[4];
#pragma unroll
      for (int i = 0; i < 4; ++i) {
        int row = wm * 64 + i * 16 + (lane & 15);
        int off = row * 128 + ((ks * 64 + (lane >> 4) * 16) ^ ((row & 7) << 4));
        af[i] = *(const bf16x8*)(sA + off);
      }
#pragma unroll
      for (int j = 0; j < 4; ++j) {
        int row = wn * 64 + j * 16 + (lane & 15);
        int off = row * 128 + ((ks * 64 + (lane >> 4) * 16) ^ ((row & 7) << 4));
        bfr[j] = *(const bf16x8*)(sB + off);
      }
#pragma unroll
      for (int i = 0; i < 4; ++i)
#pragma unroll
        for (int j = 0; j < 4; ++j)
          acc[i][j] = __builtin_amdgcn_mfma_f32_16x16x32_bf16(af[i], bfr[j], acc[i][j], 0, 0, 0);
    }
  }
  int rbase = (lane >> 4) * 4;
  int cbase = lane & 15;
#pragma unroll
  for (int i = 0; i < 4; ++i) {
#pragma unroll
    for (int j = 0; j < 4; ++j) {
      int n = bn * 128 + wn * 64 + j * 16 + cbase;
      float bv = bias[n];
#pragma unroll
      for (int r = 0; r < 4; ++r) {
        int m = bm * 128 + wm * 64 + i * 16 + rbase + r;
        float vv = acc[i][j][r] + bv;
        size_t idx = (size_t)m * Nn + n;
        if constexpr (MODE == 0) {
          ((bf16*)out)[idx] = __float2bfloat16(vv);
        } else if constexpr (MODE == 1) {
          ((float*)out)[idx] = vv + resid[idx];
        } else {
          ((bf16*)out)[idx] = __float2bfloat16(gelu_f(vv));
        }
      }
    }
  }
}

// ---------------- flash attention (causal), swapped-operand 32x32 MFMA ------
// qkv: bf16 [B*S][3072], head layout hd*192 + {0:q,64:k,128:v} + dh
// Swapped QK^T (S^T = K x Q^T) and swapped PV (O^T = V^T x P^T): q index is
// lane-local (col = lane&31), so softmax max/sum are in-register + ONE
// shfl_xor(32); P feeds PV's B-operand in-register (4 word-exchange shfls per
// 32-kv block). No P LDS round-trip. 4 waves x QBLK=32 -> 128-row q-tile per
// block; tile pairing (t, 15-t) -> uniform 34 KV-iterations per block.
__global__ __launch_bounds__(256) void k_attn(
    const bf16* __restrict__ qkv, bf16* __restrict__ outp) {
  int bh = blockIdx.x;
  int b = bh >> 4, hd = bh & 15;
  int j = blockIdx.y;                  // 0..7 (pair index)
  int tid = threadIdx.x, w = tid >> 6, lane = tid & 63;
  int ql = lane & 31;                  // q within wave tile (lane-local)
  int half = lane >> 5;                // 0/1
  __shared__ __align__(1024) char sK[2][8192];    // [64 kv][64 dh] bf16, swz
  __shared__ __align__(1024) char sVt[2][8192];   // [64 dh][64 kv] bf16, swz
  const unsigned short* qkv_u =
      (const unsigned short*)(qkv + (size_t)b * TS * 3072 + hd * 192);
  int srowK = lane >> 3;
  int sslotK = (lane & 7) ^ srowK;     // rule #21 pre-swizzled source slot
  constexpr float SCL = 0.18033688011f;  // 0.125 * log2(e); softmax in exp2 space

  uint32_t vr[16];                     // V staging regs

#define STAGE_K(KT, BUF)                                                      \
  {                                                                           \
    _Pragma("unroll")                                                         \
    for (int tt = 0; tt < 2; ++tt) {                                          \
      int chunk = w * 2 + tt;                                                 \
      int row = (KT) * 64 + chunk * 8 + srowK;                                \
      const char* g = (const char*)qkv_u + (size_t)row * 6144 + 128 +         \
                      sslotK * 16;                                            \
      gload16(g, sK[BUF] + chunk * 1024);                                     \
    }                                                                         \
  }
#define LOAD_V(KT)                                                            \
  {                                                                           \
    _Pragma("unroll")                                                         \
    for (int p = 0; p < 16; ++p)                                              \
      vr[p] = qkv_u[(size_t)((KT) * 64 + w * 16 + p) * 3072 + 128 + lane];    \
  }
#define COMMIT_V(BUF)                                                         \
  {                                                                           \
    uint32_t wd[8];                                                           \
    _Pragma("unroll")                                                         \
    for (int e = 0; e < 8; ++e) wd[e] = vr[2 * e] | (vr[2 * e + 1] << 16);    \
    _Pragma("unroll")                                                         \
    for (int u = 0; u < 2; ++u) {                                             \
      uint4 q4;                                                               \
      q4.x = wd[4 * u]; q4.y = wd[4 * u + 1];                                 \
      q4.z = wd[4 * u + 2]; q4.w = wd[4 * u + 3];                             \
      int off = lane * 128 + ((w * 32 + u * 16) ^ ((lane & 7) << 4));         \
      *(uint4*)(sVt[BUF] + off) = q4;                                         \
    }                                                                         \
  }

#pragma unroll 1
  for (int phase = 0; phase < 2; ++phase) {
    int t = phase ? (15 - j) : j;
    int qb = t * 128 + w * 32;         // wave's first q row
    int nkt = 2 * t + 2;
    int diag = qb >> 6;                // the one masked KV-tile; > diag skipped

    // Q fragments: lane holds Q[qb+ql][dh = ks*16 + 8*half + 0..7]
    const unsigned short* qrow = qkv_u + (size_t)(qb + ql) * 3072;
    bf16x8 qf[4];
#pragma unroll
    for (int ks = 0; ks < 4; ++ks)
      qf[ks] = *(const bf16x8*)(qrow + ks * 16 + 8 * half);

    float m_st = -3.0e38f, l_own = 0.0f;
    f32x16 oaccT[2];
#pragma unroll
    for (int dt = 0; dt < 2; ++dt)
#pragma unroll
      for (int r = 0; r < 16; ++r) oaccT[dt][r] = 0.0f;

    STAGE_K(0, 0);
    LOAD_V(0);
    COMMIT_V(0);
    __syncthreads();

    for (int kt = 0; kt < nkt; ++kt) {
      int cur = kt & 1;
      int nxt = cur ^ 1;
      if (kt + 1 < nkt) {              // issue-early (T14)
        STAGE_K(kt + 1, nxt);
        LOAD_V(kt + 1);
      }
      if (kt <= diag) {
        // ---- QK^T (swapped): sc[nt] = K-rows(nt*32..+31) x Q ----
        f32x16 sc[2];
#pragma unroll
        for (int nt = 0; nt < 2; ++nt) {
#pragma unroll
          for (int r = 0; r < 16; ++r) sc[nt][r] = 0.0f;
#pragma unroll
          for (int ks = 0; ks < 4; ++ks) {
            int row = nt * 32 + ql;
            int off = row * 128 + ((ks * 32 + 16 * half) ^ ((row & 7) << 4));
            bf16x8 kf = *(const bf16x8*)(sK[cur] + off);
            sc[nt] = __builtin_amdgcn_mfma_f32_32x32x16_bf16(kf, qf[ks], sc[nt], 0, 0, 0);
          }
        }
        // ---- scale (+mask on diagonal tile only), in-lane max ----
        float pm = -3.0e38f;
        if (kt == diag) {
#pragma unroll
          for (int nt = 0; nt < 2; ++nt)
#pragma unroll
            for (int r = 0; r < 16; ++r) {
              int kvg = kt * 64 + nt * 32 + (r & 3) + 8 * (r >> 2) + 4 * half;
              float s = sc[nt][r] * SCL;
              s = (kvg <= qb + ql) ? s : -3.0e38f;
              sc[nt][r] = s;
              pm = fmaxf(pm, s);
            }
        } else {
#pragma unroll
          for (int nt = 0; nt < 2; ++nt)
#pragma unroll
            for (int r = 0; r < 16; ++r) {
              float s = sc[nt][r] * SCL;
              sc[nt][r] = s;
              pm = fmaxf(pm, s);
            }
        }
        pm = fmaxf(pm, __shfl_xor(pm, 32));
        float mn = fmaxf(m_st, pm);
        float f = exp2f(m_st - mn);
        m_st = mn;
        // ---- exp2 + in-lane sum (l kept split per half; combined at end) ---
        float ts = 0.0f;
#pragma unroll
        for (int nt = 0; nt < 2; ++nt)
#pragma unroll
          for (int r = 0; r < 16; ++r) {
            float p = exp2f(sc[nt][r] - mn);
            sc[nt][r] = p;
            ts += p;
          }
        l_own = l_own * f + ts;
#pragma unroll
        for (int dt = 0; dt < 2; ++dt)
#pragma unroll
          for (int r = 0; r < 16; ++r) oaccT[dt][r] *= f;
        // ---- PV (swapped): oaccT[dt] += V^T x P^T ----
#pragma unroll
        for (int nt = 0; nt < 2; ++nt) {
          // pack P to bf16 words: w8[g*2+e] = kv-local (8g+4*half+2e, +1)
          uint32_t w8[8];
#pragma unroll
          for (int g = 0; g < 4; ++g)
#pragma unroll
            for (int e = 0; e < 2; ++e)
              w8[g * 2 + e] = (uint32_t)f2bfbits(sc[nt][4 * g + 2 * e]) |
                              ((uint32_t)f2bfbits(sc[nt][4 * g + 2 * e + 1]) << 16);
          // exchange with partner lane (lane^32)
          uint32_t rcv[2][2];
#pragma unroll
          for (int s = 0; s < 2; ++s)
#pragma unroll
            for (int e = 0; e < 2; ++e) {
              uint32_t snd = half ? w8[4 * s + e] : w8[4 * s + 2 + e];
              rcv[s][e] = (uint32_t)__shfl_xor((int)snd, 32);
            }
#pragma unroll
          for (int s = 0; s < 2; ++s) {
            union { uint32_t u[4]; bf16x8 v; } pf;
            if (half == 0) {
              pf.u[0] = w8[4 * s]; pf.u[1] = w8[4 * s + 1];
              pf.u[2] = rcv[s][0]; pf.u[3] = rcv[s][1];
            } else {
              pf.u[0] = rcv[s][0]; pf.u[1] = rcv[s][1];
              pf.u[2] = w8[4 * s + 2]; pf.u[3] = w8[4 * s + 3];
            }
#pragma unroll
            for (int dt = 0; dt < 2; ++dt) {
              int row = dt * 32 + ql;
              int off = row * 128 +
                        ((nt * 64 + s * 32 + 16 * half) ^ ((row & 7) << 4));
              bf16x8 vtf = *(const bf16x8*)(sVt[cur] + off);
              oaccT[dt] = __builtin_amdgcn_mfma_f32_32x32x16_bf16(vtf, pf.v, oaccT[dt], 0, 0, 0);
            }
          }
        }
      }
      if (kt + 1 < nkt) COMMIT_V(nxt);   // write-late
      __syncthreads();
    }
    // ---- finalize: O[q][dh], dh = dt*32 + 8g + 4*half + e ----
    float l_tot = l_own + __shfl_xor(l_own, 32);
    float inv = 1.0f / l_tot;
    int qg = qb + ql;
    bf16* orow = outp + (size_t)(b * TS + qg) * TD + hd * 64;
#pragma unroll
    for (int dt = 0; dt < 2; ++dt)
#pragma unroll
      for (int g = 0; g < 4; ++g) {
        int dh0 = dt * 32 + 8 * g + 4 * half;
        ushort4 s4;
        s4.x = f2bfbits(oaccT[dt][4 * g] * inv);
        s4.y = f2bfbits(oaccT[dt][4 * g + 1] * inv);
        s4.z = f2bfbits(oaccT[dt][4 * g + 2] * inv);
        s4.w = f2bfbits(oaccT[dt][4 * g + 3] * inv);
        *(ushort4*)(orow + dh0) = s4;
      }
  }
#undef STAGE_K
#undef LOAD_V
#undef COMMIT_V
}

// ---------------- launch -----------------------------------------------------
extern "C" void kernel_launch(void* const* d_in, const int* in_sizes, int n_in,
                              void* d_out, int out_size, void* d_ws, size_t ws_size,
                              hipStream_t stream) {
  const float* x      = (const float*)d_in[0];
  const float* gamma1 = (const float*)d_in[1];
  const float* beta1  = (const float*)d_in[2];
  const float* W_qkv  = (const float*)d_in[3];
  const float* b_qkv  = (const float*)d_in[4];
  const float* W_o    = (const float*)d_in[5];
  const float* b_o    = (const float*)d_in[6];
  const float* gamma2 = (const float*)d_in[7];
  const float* beta2  = (const float*)d_in[8];
  const float* W_up   = (const float*)d_in[9];
  const float* b_up   = (const float*)d_in[10];
  const float* W_down = (const float*)d_in[11];
  const float* b_down = (const float*)d_in[12];

  char* ws = (char*)d_ws;
  bf16*  wt_qkv  = (bf16*)(ws + 0);                  //  6291456
  bf16*  wt_o    = (bf16*)(ws + 6291456);            //  2097152
  bf16*  wt_up   = (bf16*)(ws + 8388608);            //  8388608
  bf16*  wt_down = (bf16*)(ws + 16777216);           //  8388608
  bf16*  h1      = (bf16*)(ws + 25165824);           //  8388608
  bf16*  qkvb    = (bf16*)(ws + 33554432);           // 25165824
  bf16*  ob      = (bf16*)(ws + 58720256);           //  8388608
  float* attn_o  = (float*)(ws + 67108864);          // 16777216
  bf16*  h2      = (bf16*)(ws + 83886080);           //  8388608
  bf16*  ub      = (bf16*)(ws + 92274688);           // 33554432
  float* outf    = (float*)d_out;

  k_transpose_bf16<<<dim3(16, 48), 256, 0, stream>>>(W_qkv, wt_qkv, 1024, 3072);
  k_transpose_bf16<<<dim3(16, 16), 256, 0, stream>>>(W_o, wt_o, 1024, 1024);
  k_transpose_bf16<<<dim3(16, 64), 256, 0, stream>>>(W_up, wt_up, 1024, 4096);
  k_transpose_bf16<<<dim3(64, 16), 256, 0, stream>>>(W_down, wt_down, 4096, 1024);

  k_layernorm<<<TM, 256, 0, stream>>>(x, gamma1, beta1, h1);
  k_gemm<0><<<dim3(24, 32), 256, 0, stream>>>(h1, wt_qkv, b_qkv, nullptr, qkvb, TM, 3072, 1024);
  k_attn<<<dim3(64, 8), 256, 0, stream>>>(qkvb, ob);
  k_gemm<1><<<dim3(8, 32), 256, 0, stream>>>(ob, wt_o, b_o, x, attn_o, TM, 1024, 1024);
  k_layernorm<<<TM, 256, 0, stream>>>(attn_o, gamma2, beta2, h2);
  k_gemm<2><<<dim3(32, 32), 256, 0, stream>>>(h2, wt_up, b_up, nullptr, ub, TM, 4096, 1024);
  k_gemm<1><<<dim3(8, 32), 256, 0, stream>>>(ub, wt_down, b_down, attn_o, outf, TM, 1024, 4096);
}

// Round 5
// 372.668 us; speedup vs baseline: 1.9198x; 1.3111x over previous
//
#include <hip/hip_runtime.h>
#include <hip/hip_bf16.h>
#include <stdint.h>

// Problem constants: B=2, S=2048, D=1024, H=16, DH=64
constexpr int TS = 2048;
constexpr int TD = 1024;
constexpr int TM = 4096;        // B*S rows
constexpr float GELU_C = 0.7978845608f;

typedef __hip_bfloat16 bf16;
typedef __attribute__((ext_vector_type(8))) short bf16x8;
typedef __attribute__((ext_vector_type(4))) float f32x4;
typedef __attribute__((ext_vector_type(16))) float f32x16;

__device__ __forceinline__ void gload16(const void* g, void* l) {
  __builtin_amdgcn_global_load_lds(
      (const __attribute__((address_space(1))) void*)g,
      (__attribute__((address_space(3))) void*)l, 16, 0, 0);
}

__device__ __forceinline__ unsigned short f2bfbits(float f) {
  bf16 h = __float2bfloat16(f);
  unsigned short u;
  __builtin_memcpy(&u, &h, 2);
  return u;
}

// packed f32->bf16 (RNE) pair: no builtin on gfx950, inline asm per T12
__device__ __forceinline__ uint32_t cvtpk_bf16(float lo, float hi) {
  uint32_t r;
  asm("v_cvt_pk_bf16_f32 %0, %1, %2" : "=v"(r) : "v"(lo), "v"(hi));
  return r;
}
// raw 2^x
__device__ __forceinline__ float ex2(float x) {
  float r;
  asm("v_exp_f32 %0, %1" : "=v"(r) : "v"(x));
  return r;
}

__device__ __forceinline__ float gelu_f(float x) {
  float x3 = x * x * x;
  return 0.5f * x * (1.0f + tanhf(GELU_C * (x + 0.044715f * x3)));
}

// ---------------- weight convert+transpose: W[K][N] f32 -> Wt[N][K] bf16 ----
__global__ __launch_bounds__(256) void k_transpose_bf16(
    const float* __restrict__ W, bf16* __restrict__ Wt, int K, int N) {
  __shared__ float t[64][65];
  int k0 = blockIdx.x * 64, n0 = blockIdx.y * 64;
  int tid = threadIdx.x;
  int c = tid & 63, r0 = tid >> 6;
#pragma unroll
  for (int i = 0; i < 16; ++i) {
    int r = r0 + i * 4;
    t[r][c] = W[(size_t)(k0 + r) * N + n0 + c];
  }
  __syncthreads();
#pragma unroll
  for (int i = 0; i < 16; ++i) {
    int r = r0 + i * 4;   // row of Wt = n0+r
    Wt[(size_t)(n0 + r) * K + k0 + c] = __float2bfloat16(t[c][r]);
  }
}

// ---------------- LayerNorm (fp32 in, bf16 out), row = 1024 -----------------
__global__ __launch_bounds__(256) void k_layernorm(
    const float* __restrict__ x, const float* __restrict__ gamma,
    const float* __restrict__ beta, bf16* __restrict__ out) {
  int row = blockIdx.x;
  const float* xr = x + (size_t)row * TD;
  int tid = threadIdx.x;
  float4 v = ((const float4*)xr)[tid];
  float s = v.x + v.y + v.z + v.w;
  float ss = v.x * v.x + v.y * v.y + v.z * v.z + v.w * v.w;
#pragma unroll
  for (int off = 32; off; off >>= 1) {
    s += __shfl_down(s, off);
    ss += __shfl_down(ss, off);
  }
  __shared__ float red[8];
  __shared__ float stat[2];
  int wid = tid >> 6, lane = tid & 63;
  if (lane == 0) { red[wid] = s; red[4 + wid] = ss; }
  __syncthreads();
  if (tid == 0) {
    float S1 = red[0] + red[1] + red[2] + red[3];
    float S2 = red[4] + red[5] + red[6] + red[7];
    float mean = S1 / (float)TD;
    float var = (S2 - S1 * mean) / (float)(TD - 1);
    var = fmaxf(var, 0.0f);
    stat[0] = mean;
    stat[1] = 1.0f / (sqrtf(var) + 1e-5f);
  }
  __syncthreads();
  float mean = stat[0], rstd = stat[1];
  float4 g = ((const float4*)gamma)[tid];
  float4 bb = ((const float4*)beta)[tid];
  ushort4 r4;
  r4.x = f2bfbits(g.x * (v.x - mean) * rstd + bb.x);
  r4.y = f2bfbits(g.y * (v.y - mean) * rstd + bb.y);
  r4.z = f2bfbits(g.z * (v.z - mean) * rstd + bb.z);
  r4.w = f2bfbits(g.w * (v.w - mean) * rstd + bb.w);
  ((ushort4*)(out + (size_t)row * TD))[tid] = r4;
}

// ---------------- bf16 MFMA GEMM: C = A[M][K] @ Bt[N][K]^T + epilogue -------
// 128x128 tile, BK=64, 4 waves (2x2), m97 structure + st-swizzled LDS.
template <int MODE>
__global__ __launch_bounds__(256) void k_gemm(
    const bf16* __restrict__ A, const bf16* __restrict__ Bt,
    const float* __restrict__ bias, const float* __restrict__ resid,
    void* __restrict__ out, int Mm, int Nn, int Kk) {
  __shared__ __align__(1024) char smem[32768];   // sA 16KB | sB 16KB
  char* sA = smem;
  char* sB = smem + 16384;
  int bm = blockIdx.y, bn = blockIdx.x;
  int tid = threadIdx.x, w = tid >> 6, lane = tid & 63;
  int wm = w >> 1, wn = w & 1;
  f32x4 acc[4][4] = {};
  size_t arow0 = (size_t)bm * 128;
  size_t brow0 = (size_t)bn * 128;
  int srow = lane >> 3;                 // row within 8-row chunk
  int sslot = (lane & 7) ^ srow;        // pre-swizzled logical 16B slot (rule #21)
  int nkt = Kk >> 6;
  for (int kt = 0; kt < nkt; ++kt) {
    __syncthreads();
#pragma unroll
    for (int t = 0; t < 4; ++t) {
      int chunk = w * 4 + t;
      int row = chunk * 8 + srow;
      const char* g = (const char*)(A + (arow0 + row) * (size_t)Kk + kt * 64) + sslot * 16;
      gload16(g, sA + chunk * 1024);
    }
#pragma unroll
    for (int t = 0; t < 4; ++t) {
      int chunk = w * 4 + t;
      int row = chunk * 8 + srow;
      const char* g = (const char*)(Bt + (brow0 + row) * (size_t)Kk + kt * 64) + sslot * 16;
      gload16(g, sB + chunk * 1024);
    }
    __syncthreads();
#pragma unroll
    for (int ks = 0; ks < 2; ++ks) {
      bf16x8 af[4], bfr[4];
#pragma unroll
      for (int i = 0; i < 4; ++i) {
        int row = wm * 64 + i * 16 + (lane & 15);
        int off = row * 128 + ((ks * 64 + (lane >> 4) * 16) ^ ((row & 7) << 4));
        af[i] = *(const bf16x8*)(sA + off);
      }
#pragma unroll
      for (int j = 0; j < 4; ++j) {
        int row = wn * 64 + j * 16 + (lane & 15);
        int off = row * 128 + ((ks * 64 + (lane >> 4) * 16) ^ ((row & 7) << 4));
        bfr[j] = *(const bf16x8*)(sB + off);
      }
#pragma unroll
      for (int i = 0; i < 4; ++i)
#pragma unroll
        for (int j = 0; j < 4; ++j)
          acc[i][j] = __builtin_amdgcn_mfma_f32_16x16x32_bf16(af[i], bfr[j], acc[i][j], 0, 0, 0);
    }
  }
  int rbase = (lane >> 4) * 4;
  int cbase = lane & 15;
#pragma unroll
  for (int i = 0; i < 4; ++i) {
#pragma unroll
    for (int j = 0; j < 4; ++j) {
      int n = bn * 128 + wn * 64 + j * 16 + cbase;
      float bv = bias[n];
#pragma unroll
      for (int r = 0; r < 4; ++r) {
        int m = bm * 128 + wm * 64 + i * 16 + rbase + r;
        float vv = acc[i][j][r] + bv;
        size_t idx = (size_t)m * Nn + n;
        if constexpr (MODE == 0) {
          ((bf16*)out)[idx] = __float2bfloat16(vv);
        } else if constexpr (MODE == 1) {
          ((float*)out)[idx] = vv + resid[idx];
        } else {
          ((bf16*)out)[idx] = __float2bfloat16(gelu_f(vv));
        }
      }
    }
  }
}

// ---------------- flash attention (causal), swapped-operand 32x32 MFMA ------
// qkv: bf16 [B*S][3072], head layout hd*192 + {0:q,64:k,128:v} + dh
// One block = one 64-q tile T: 4 waves = 2 qsub (32 q) x 2 ntw (32-kv column
// half of each staged 64-kv tile). ntw partials merged in-LDS at the end.
// Swapped QK^T/PV keep q lane-local: tree max/sum in-register + 1 shfl.
// LPT: T = 31 - blockIdx.y so longest blocks dispatch first.
__global__ __launch_bounds__(256, 4) void k_attn(
    const bf16* __restrict__ qkv, bf16* __restrict__ outp) {
  int bh = blockIdx.x;                 // 0..31
  int b = bh >> 4, hd = bh & 15;
  int T = 31 - (int)blockIdx.y;        // q-tile index, 64 rows
  int tid = threadIdx.x, w = tid >> 6, lane = tid & 63;
  int qsub = w >> 1, ntw = w & 1;
  int ql = lane & 31;
  int half = lane >> 5;
  __shared__ __align__(1024) char smem[32768];
  char* sK0 = smem;                    // sK[buf] = smem + buf*8192   (16 KB)
  char* sV0 = smem + 16384;            // sVt[buf] = sV0 + buf*8192   (16 KB)
  const unsigned short* qkv_u =
      (const unsigned short*)(qkv + (size_t)b * TS * 3072 + hd * 192);
  int srowK = lane >> 3;
  int sslotK = (lane & 7) ^ srowK;     // rule #21 pre-swizzled source slot
  constexpr float SCL = 0.18033688011f;  // 0.125 * log2(e)

  int q0 = T * 64 + qsub * 32;
  int nkt = T + 1;
  int qlim = qsub * 32 + ql;           // kv-local causal bound on tile T

  // Q fragments: lane holds Q[q0+ql][dh = ks*16 + 8*half + 0..7]
  const unsigned short* qrow = qkv_u + (size_t)(q0 + ql) * 3072;
  bf16x8 qf[4];
#pragma unroll
  for (int ks = 0; ks < 4; ++ks)
    qf[ks] = *(const bf16x8*)(qrow + ks * 16 + 8 * half);

  float m_st = -3.0e38f, l_own = 0.0f;
  f32x16 oaccT[2];
#pragma unroll
  for (int dt = 0; dt < 2; ++dt)
#pragma unroll
    for (int r = 0; r < 16; ++r) oaccT[dt][r] = 0.0f;

  uint32_t vr[16];                     // V staging regs

#define STAGE_K(KT, BUF)                                                      \
  {                                                                           \
    _Pragma("unroll")                                                         \
    for (int tt = 0; tt < 2; ++tt) {                                          \
      int chunk = w * 2 + tt;                                                 \
      int row = (KT) * 64 + chunk * 8 + srowK;                                \
      const char* g = (const char*)qkv_u + (size_t)row * 6144 + 128 +         \
                      sslotK * 16;                                            \
      gload16(g, sK0 + (BUF) * 8192 + chunk * 1024);                          \
    }                                                                         \
  }
#define LOAD_V(KT)                                                            \
  {                                                                           \
    _Pragma("unroll")                                                         \
    for (int p = 0; p < 16; ++p)                                              \
      vr[p] = qkv_u[(size_t)((KT) * 64 + w * 16 + p) * 3072 + 128 + lane];    \
  }
#define COMMIT_V(BUF)                                                         \
  {                                                                           \
    uint32_t wd[8];                                                           \
    _Pragma("unroll")                                                         \
    for (int e = 0; e < 8; ++e) wd[e] = vr[2 * e] | (vr[2 * e + 1] << 16);    \
    _Pragma("unroll")                                                         \
    for (int u = 0; u < 2; ++u) {                                             \
      uint4 q4;                                                               \
      q4.x = wd[4 * u]; q4.y = wd[4 * u + 1];                                 \
      q4.z = wd[4 * u + 2]; q4.w = wd[4 * u + 3];                             \
      int off = lane * 128 + ((w * 32 + u * 16) ^ ((lane & 7) << 4));         \
      *(uint4*)(sV0 + (BUF) * 8192 + off) = q4;                               \
    }                                                                         \
  }

  STAGE_K(0, 0);
  LOAD_V(0);
  COMMIT_V(0);
  __syncthreads();

  for (int kt = 0; kt < nkt; ++kt) {
    int cur = kt & 1;
    int nxt = cur ^ 1;
    if (kt + 1 < nkt) {                // issue-early (T14)
      STAGE_K(kt + 1, nxt);
      LOAD_V(kt + 1);
    }
    bool act = (kt < T) | (ntw <= qsub);
    if (act) {
      // ---- QK^T (swapped): sc = K-rows(ntw*32..+31) x Q ----
      f32x16 sc;
#pragma unroll
      for (int r = 0; r < 16; ++r) sc[r] = 0.0f;
#pragma unroll
      for (int ks = 0; ks < 4; ++ks) {
        int row = ntw * 32 + ql;
        int off = row * 128 + ((ks * 32 + 16 * half) ^ ((row & 7) << 4));
        bf16x8 kf = *(const bf16x8*)(sK0 + cur * 8192 + off);
        sc = __builtin_amdgcn_mfma_f32_32x32x16_bf16(kf, qf[ks], sc, 0, 0, 0);
      }
      // ---- scale (+mask only on the diagonal tile) ----
      if (kt == T) {
#pragma unroll
        for (int r = 0; r < 16; ++r) {
          int loc = ntw * 32 + (r & 3) + 8 * (r >> 2) + 4 * half;
          float s = sc[r] * SCL;
          sc[r] = (loc <= qlim) ? s : -3.0e38f;
        }
      } else {
#pragma unroll
        for (int r = 0; r < 16; ++r) sc[r] *= SCL;
      }
      // ---- tree max + one cross-half shfl ----
      float t8[8];
#pragma unroll
      for (int e = 0; e < 8; ++e) t8[e] = fmaxf(sc[e], sc[e + 8]);
#pragma unroll
      for (int e = 0; e < 4; ++e) t8[e] = fmaxf(t8[e], t8[e + 4]);
      float pm = fmaxf(fmaxf(t8[0], t8[2]), fmaxf(t8[1], t8[3]));
      pm = fmaxf(pm, __shfl_xor(pm, 32));
      // ---- T13 defer-rescale (11.5 = 8/ln2 headroom in log2 space) ----
      if (!__all(pm <= m_st + 11.5f)) {
        float mn = fmaxf(m_st, pm);
        float f = ex2(m_st - mn);
        l_own *= f;
#pragma unroll
        for (int dt = 0; dt < 2; ++dt)
#pragma unroll
          for (int r = 0; r < 16; ++r) oaccT[dt][r] *= f;
        m_st = mn;
      }
      // ---- exp2 + tree sum ----
#pragma unroll
      for (int r = 0; r < 16; ++r) sc[r] = ex2(sc[r] - m_st);
#pragma unroll
      for (int e = 0; e < 8; ++e) t8[e] = sc[e] + sc[e + 8];
#pragma unroll
      for (int e = 0; e < 4; ++e) t8[e] = t8[e] + t8[e + 4];
      l_own += (t8[0] + t8[2]) + (t8[1] + t8[3]);
      // ---- pack P to bf16 (cvt_pk) + cross-half word exchange ----
      uint32_t w8[8];
#pragma unroll
      for (int g = 0; g < 4; ++g)
#pragma unroll
        for (int e = 0; e < 2; ++e)
          w8[g * 2 + e] = cvtpk_bf16(sc[4 * g + 2 * e], sc[4 * g + 2 * e + 1]);
      uint32_t rcv[2][2];
#pragma unroll
      for (int s = 0; s < 2; ++s)
#pragma unroll
        for (int e = 0; e < 2; ++e) {
          uint32_t snd = half ? w8[4 * s + e] : w8[4 * s + 2 + e];
          rcv[s][e] = (uint32_t)__shfl_xor((int)snd, 32);
        }
      // ---- PV (swapped): oaccT[dt] += V^T x P^T ----
#pragma unroll
      for (int s = 0; s < 2; ++s) {
        union { uint32_t u[4]; bf16x8 v; } pf;
        if (half == 0) {
          pf.u[0] = w8[4 * s]; pf.u[1] = w8[4 * s + 1];
          pf.u[2] = rcv[s][0]; pf.u[3] = rcv[s][1];
        } else {
          pf.u[0] = rcv[s][0]; pf.u[1] = rcv[s][1];
          pf.u[2] = w8[4 * s + 2]; pf.u[3] = w8[4 * s + 3];
        }
#pragma unroll
        for (int dt = 0; dt < 2; ++dt) {
          int row = dt * 32 + ql;
          int off = row * 128 +
                    ((ntw * 64 + s * 32 + 16 * half) ^ ((row & 7) << 4));
          bf16x8 vtf = *(const bf16x8*)(sV0 + cur * 8192 + off);
          oaccT[dt] = __builtin_amdgcn_mfma_f32_32x32x16_bf16(vtf, pf.v, oaccT[dt], 0, 0, 0);
        }
      }
    }
    if (kt + 1 < nkt) COMMIT_V(nxt);   // write-late
    __syncthreads();
  }

  // ---- ntw-partner merge via LDS (K/V buffers dead now) ----
  float l_tot = l_own + __shfl_xor(l_own, 32);
  float* scr = (float*)smem;           // [idx 0..33][qsub 0..1][lane 0..63]
  if (ntw == 1) {
    scr[(0 * 2 + qsub) * 64 + lane] = m_st;
    scr[(1 * 2 + qsub) * 64 + lane] = l_tot;
#pragma unroll
    for (int dt = 0; dt < 2; ++dt)
#pragma unroll
      for (int r = 0; r < 16; ++r)
        scr[((2 + dt * 16 + r) * 2 + qsub) * 64 + lane] = oaccT[dt][r];
  }
  __syncthreads();
  if (ntw == 0) {
    float mB = scr[(0 * 2 + qsub) * 64 + lane];
    float lB = scr[(1 * 2 + qsub) * 64 + lane];
    float m = fmaxf(m_st, mB);
    float wa = ex2(m_st - m), wb = ex2(mB - m);
    float linv = 1.0f / (l_tot * wa + lB * wb);
    int qg = q0 + ql;
    bf16* orow = outp + (size_t)(b * TS + qg) * TD + hd * 64;
#pragma unroll
    for (int dt = 0; dt < 2; ++dt)
#pragma unroll
      for (int g = 0; g < 4; ++g) {
        ushort4 s4;
        float o0, o1, o2, o3;
        o0 = (oaccT[dt][4 * g] * wa +
              scr[((2 + dt * 16 + 4 * g) * 2 + qsub) * 64 + lane] * wb) * linv;
        o1 = (oaccT[dt][4 * g + 1] * wa +
              scr[((2 + dt * 16 + 4 * g + 1) * 2 + qsub) * 64 + lane] * wb) * linv;
        o2 = (oaccT[dt][4 * g + 2] * wa +
              scr[((2 + dt * 16 + 4 * g + 2) * 2 + qsub) * 64 + lane] * wb) * linv;
        o3 = (oaccT[dt][4 * g + 3] * wa +
              scr[((2 + dt * 16 + 4 * g + 3) * 2 + qsub) * 64 + lane] * wb) * linv;
        s4.x = f2bfbits(o0); s4.y = f2bfbits(o1);
        s4.z = f2bfbits(o2); s4.w = f2bfbits(o3);
        *(ushort4*)(orow + dt * 32 + 8 * g + 4 * half) = s4;
      }
  }
#undef STAGE_K
#undef LOAD_V
#undef COMMIT_V
}

// ---------------- launch -----------------------------------------------------
extern "C" void kernel_launch(void* const* d_in, const int* in_sizes, int n_in,
                              void* d_out, int out_size, void* d_ws, size_t ws_size,
                              hipStream_t stream) {
  const float* x      = (const float*)d_in[0];
  const float* gamma1 = (const float*)d_in[1];
  const float* beta1  = (const float*)d_in[2];
  const float* W_qkv  = (const float*)d_in[3];
  const float* b_qkv  = (const float*)d_in[4];
  const float* W_o    = (const float*)d_in[5];
  const float* b_o    = (const float*)d_in[6];
  const float* gamma2 = (const float*)d_in[7];
  const float* beta2  = (const float*)d_in[8];
  const float* W_up   = (const float*)d_in[9];
  const float* b_up   = (const float*)d_in[10];
  const float* W_down = (const float*)d_in[11];
  const float* b_down = (const float*)d_in[12];

  char* ws = (char*)d_ws;
  bf16*  wt_qkv  = (bf16*)(ws + 0);                  //  6291456
  bf16*  wt_o    = (bf16*)(ws + 6291456);            //  2097152
  bf16*  wt_up   = (bf16*)(ws + 8388608);            //  8388608
  bf16*  wt_down = (bf16*)(ws + 16777216);           //  8388608
  bf16*  h1      = (bf16*)(ws + 25165824);           //  8388608
  bf16*  qkvb    = (bf16*)(ws + 33554432);           // 25165824
  bf16*  ob      = (bf16*)(ws + 58720256);           //  8388608
  float* attn_o  = (float*)(ws + 67108864);          // 16777216
  bf16*  h2      = (bf16*)(ws + 83886080);           //  8388608
  bf16*  ub      = (bf16*)(ws + 92274688);           // 33554432
  float* outf    = (float*)d_out;

  k_transpose_bf16<<<dim3(16, 48), 256, 0, stream>>>(W_qkv, wt_qkv, 1024, 3072);
  k_transpose_bf16<<<dim3(16, 16), 256, 0, stream>>>(W_o, wt_o, 1024, 1024);
  k_transpose_bf16<<<dim3(16, 64), 256, 0, stream>>>(W_up, wt_up, 1024, 4096);
  k_transpose_bf16<<<dim3(64, 16), 256, 0, stream>>>(W_down, wt_down, 4096, 1024);

  k_layernorm<<<TM, 256, 0, stream>>>(x, gamma1, beta1, h1);
  k_gemm<0><<<dim3(24, 32), 256, 0, stream>>>(h1, wt_qkv, b_qkv, nullptr, qkvb, TM, 3072, 1024);
  k_attn<<<dim3(32, 32), 256, 0, stream>>>(qkvb, ob);
  k_gemm<1><<<dim3(8, 32), 256, 0, stream>>>(ob, wt_o, b_o, x, attn_o, TM, 1024, 1024);
  k_layernorm<<<TM, 256, 0, stream>>>(attn_o, gamma2, beta2, h2);
  k_gemm<2><<<dim3(32, 32), 256, 0, stream>>>(h2, wt_up, b_up, nullptr, ub, TM, 4096, 1024);
  k_gemm<1><<<dim3(8, 32), 256, 0, stream>>>(ub, wt_down, b_down, attn_o, outf, TM, 1024, 4096);
}

// Round 11
// 347.410 us; speedup vs baseline: 2.0594x; 1.0727x over previous
//
#include <hip/hip_runtime.h>
#include <hip/hip_bf16.h>
#include <stdint.h>

// Problem constants: B=2, S=2048, D=1024, H=16, DH=64
constexpr int TS = 2048;
constexpr int TD = 1024;
constexpr int TM = 4096;        // B*S rows
constexpr float GELU_C = 0.7978845608f;

typedef __hip_bfloat16 bf16;
typedef __attribute__((ext_vector_type(8))) short bf16x8;
typedef __attribute__((ext_vector_type(4))) float f32x4;
typedef __attribute__((ext_vector_type(16))) float f32x16;

__device__ __forceinline__ void gload16(const void* g, void* l) {
  __builtin_amdgcn_global_load_lds(
      (const __attribute__((address_space(1))) void*)g,
      (__attribute__((address_space(3))) void*)l, 16, 0, 0);
}

__device__ __forceinline__ unsigned short f2bfbits(float f) {
  bf16 h = __float2bfloat16(f);
  unsigned short u;
  __builtin_memcpy(&u, &h, 2);
  return u;
}

// packed f32->bf16 (RNE) pair: no builtin on gfx950, inline asm per T12
__device__ __forceinline__ uint32_t cvtpk_bf16(float lo, float hi) {
  uint32_t r;
  asm("v_cvt_pk_bf16_f32 %0, %1, %2" : "=v"(r) : "v"(lo), "v"(hi));
  return r;
}
// raw 2^x
__device__ __forceinline__ float ex2(float x) {
  float r;
  asm("v_exp_f32 %0, %1" : "=v"(r) : "v"(x));
  return r;
}

// gelu via exp2: tanh(u) = 1 - 2/(e+1), e = 2^(2u*log2e).
// (1-2/(e+1) form, NOT (e-1)/(e+1): saturates to 1 at e=+inf instead of NaN.)
__device__ __forceinline__ float gelu_f(float x) {
  float u = GELU_C * (x + 0.044715f * x * x * x);
  float e = ex2(u * 2.8853900818f);          // exp(2u)
  float th = 1.0f - 2.0f / (e + 1.0f);
  return 0.5f * x * (1.0f + th);
}

// ---------------- weight convert+transpose: W[K][N] f32 -> Wt[N][K] bf16 ----
__global__ __launch_bounds__(256) void k_transpose_bf16(
    const float* __restrict__ W, bf16* __restrict__ Wt, int K, int N) {
  __shared__ float t[64][65];
  int k0 = blockIdx.x * 64, n0 = blockIdx.y * 64;
  int tid = threadIdx.x;
  int c = tid & 63, r0 = tid >> 6;
#pragma unroll
  for (int i = 0; i < 16; ++i) {
    int r = r0 + i * 4;
    t[r][c] = W[(size_t)(k0 + r) * N + n0 + c];
  }
  __syncthreads();
#pragma unroll
  for (int i = 0; i < 16; ++i) {
    int r = r0 + i * 4;   // row of Wt = n0+r
    Wt[(size_t)(n0 + r) * K + k0 + c] = __float2bfloat16(t[c][r]);
  }
}

// ---------------- LayerNorm (fp32 in, bf16 out), row = 1024 -----------------
__global__ __launch_bounds__(256) void k_layernorm(
    const float* __restrict__ x, const float* __restrict__ gamma,
    const float* __restrict__ beta, bf16* __restrict__ out) {
  int row = blockIdx.x;
  const float* xr = x + (size_t)row * TD;
  int tid = threadIdx.x;
  float4 v = ((const float4*)xr)[tid];
  float s = v.x + v.y + v.z + v.w;
  float ss = v.x * v.x + v.y * v.y + v.z * v.z + v.w * v.w;
#pragma unroll
  for (int off = 32; off; off >>= 1) {
    s += __shfl_down(s, off);
    ss += __shfl_down(ss, off);
  }
  __shared__ float red[8];
  __shared__ float stat[2];
  int wid = tid >> 6, lane = tid & 63;
  if (lane == 0) { red[wid] = s; red[4 + wid] = ss; }
  __syncthreads();
  if (tid == 0) {
    float S1 = red[0] + red[1] + red[2] + red[3];
    float S2 = red[4] + red[5] + red[6] + red[7];
    float mean = S1 / (float)TD;
    float var = (S2 - S1 * mean) / (float)(TD - 1);
    var = fmaxf(var, 0.0f);
    stat[0] = mean;
    stat[1] = 1.0f / (sqrtf(var) + 1e-5f);
  }
  __syncthreads();
  float mean = stat[0], rstd = stat[1];
  float4 g = ((const float4*)gamma)[tid];
  float4 bb = ((const float4*)beta)[tid];
  ushort4 r4;
  r4.x = f2bfbits(g.x * (v.x - mean) * rstd + bb.x);
  r4.y = f2bfbits(g.y * (v.y - mean) * rstd + bb.y);
  r4.z = f2bfbits(g.z * (v.z - mean) * rstd + bb.z);
  r4.w = f2bfbits(g.w * (v.w - mean) * rstd + bb.w);
  ((ushort4*)(out + (size_t)row * TD))[tid] = r4;
}

// ---------------- bf16 MFMA GEMM: C = A[M][K] @ Bt[N][K]^T + epilogue -------
// BM x 128 tile, BK=64. BM=128: 2x2 waves, 64x64 each. BM=64: 1x4 waves,
// 64x32 each (doubles grid for N=1024 shapes -> 2 blocks/CU latency hiding).
// 1-D grid; in-kernel XCD swizzle (T1) + bm-fastest decomposition.
// MODE 0: out bf16 = acc + bias
// MODE 1: out f32  = acc + bias + resid
// MODE 2: out bf16 = gelu(acc + bias)
template <int MODE, int BM>
__global__ __launch_bounds__(256) void k_gemm(
    const bf16* __restrict__ A, const bf16* __restrict__ Bt,
    const float* __restrict__ bias, const float* __restrict__ resid,
    void* __restrict__ out, int Nn, int Kk) {
  constexpr int NBM = TM / BM;           // 32 (BM=128) or 64 (BM=64)
  constexpr int WN = (BM == 128) ? 2 : 4;
  constexpr int WTN = 128 / WN;          // wave tile N: 64 or 32
  constexpr int NJ = WTN / 16;           // 4 or 2
  constexpr int TA = BM / 32;            // A-chunks per wave: 4 or 2
  __shared__ __align__(1024) char smem[BM * 128 + 16384];
  char* sA = smem;                       // BM x 64 bf16, swizzled
  char* sB = smem + BM * 128;            // 128 x 64 bf16, swizzled
  int total = gridDim.x;
  int orig = blockIdx.x;
  int swz = (orig & 7) * (total >> 3) + (orig >> 3);   // bijective: total%8==0
  int bm = swz & (NBM - 1);
  int bn = swz / NBM;
  int tid = threadIdx.x, w = tid >> 6, lane = tid & 63;
  int wm = (BM == 128) ? (w >> 1) : 0;
  int wn = (BM == 128) ? (w & 1) : w;
  f32x4 acc[4][NJ] = {};
  size_t arow0 = (size_t)bm * BM;
  size_t brow0 = (size_t)bn * 128;
  int srow = lane >> 3;                 // row within 8-row chunk
  int sslot = (lane & 7) ^ srow;        // pre-swizzled logical 16B slot (rule #21)
  int nkt = Kk >> 6;
  for (int kt = 0; kt < nkt; ++kt) {
    __syncthreads();
#pragma unroll
    for (int t = 0; t < TA; ++t) {
      int chunk = w * TA + t;
      int row = chunk * 8 + srow;
      const char* g = (const char*)(A + (arow0 + row) * (size_t)Kk + kt * 64) + sslot * 16;
      gload16(g, sA + chunk * 1024);
    }
#pragma unroll
    for (int t = 0; t < 4; ++t) {
      int chunk = w * 4 + t;
      int row = chunk * 8 + srow;
      const char* g = (const char*)(Bt + (brow0 + row) * (size_t)Kk + kt * 64) + sslot * 16;
      gload16(g, sB + chunk * 1024);
    }
    __syncthreads();
#pragma unroll
    for (int ks = 0; ks < 2; ++ks) {
      bf16x8 af[4], bfr[NJ];
#pragma unroll
      for (int i = 0; i < 4; ++i) {
        int row = wm * 64 + i * 16 + (lane & 15);
        int off = row * 128 + ((ks * 64 + (lane >> 4) * 16) ^ ((row & 7) << 4));
        af[i] = *(const bf16x8*)(sA + off);
      }
#pragma unroll
      for (int j = 0; j < NJ; ++j) {
        int row = wn * WTN + j * 16 + (lane & 15);
        int off = row * 128 + ((ks * 64 + (lane >> 4) * 16) ^ ((row & 7) << 4));
        bfr[j] = *(const bf16x8*)(sB + off);
      }
#pragma unroll
      for (int i = 0; i < 4; ++i)
#pragma unroll
        for (int j = 0; j < NJ; ++j)
          acc[i][j] = __builtin_amdgcn_mfma_f32_16x16x32_bf16(af[i], bfr[j], acc[i][j], 0, 0, 0);
    }
  }
  int rbase = (lane >> 4) * 4;
  int cbase = lane & 15;
#pragma unroll
  for (int i = 0; i < 4; ++i) {
#pragma unroll
    for (int j = 0; j < NJ; ++j) {
      int n = bn * 128 + wn * WTN + j * 16 + cbase;
      float bv = bias[n];
#pragma unroll
      for (int r = 0; r < 4; ++r) {
        int m = bm * BM + wm * 64 + i * 16 + rbase + r;
        float vv = acc[i][j][r] + bv;
        size_t idx = (size_t)m * Nn + n;
        if constexpr (MODE == 0) {
          ((bf16*)out)[idx] = __float2bfloat16(vv);
        } else if constexpr (MODE == 1) {
          ((float*)out)[idx] = vv + resid[idx];
        } else {
          ((bf16*)out)[idx] = __float2bfloat16(gelu_f(vv));
        }
      }
    }
  }
}

// ---------------- flash attention (causal), swapped-operand 32x32 MFMA ------
// qkv: bf16 [B*S][3072], head layout hd*192 + {0:q,64:k,128:v} + dh
// One block = one 64-q tile T: 4 waves = 2 qsub (32 q) x 2 ntw (32-kv column
// half of each staged 64-kv tile). ntw partials merged in-LDS at the end.
// Swapped QK^T/PV keep q lane-local: tree max/sum in-register + 1 shfl.
// LPT: T = 31 - blockIdx.y so longest blocks dispatch first.
__global__ __launch_bounds__(256, 4) void k_attn(
    const bf16* __restrict__ qkv, bf16* __restrict__ outp) {
  int bh = blockIdx.x;                 // 0..31
  int b = bh >> 4, hd = bh & 15;
  int T = 31 - (int)blockIdx.y;        // q-tile index, 64 rows
  int tid = threadIdx.x, w = tid >> 6, lane = tid & 63;
  int qsub = w >> 1, ntw = w & 1;
  int ql = lane & 31;
  int half = lane >> 5;
  __shared__ __align__(1024) char smem[32768];
  char* sK0 = smem;                    // sK[buf] = smem + buf*8192   (16 KB)
  char* sV0 = smem + 16384;            // sVt[buf] = sV0 + buf*8192   (16 KB)
  const unsigned short* qkv_u =
      (const unsigned short*)(qkv + (size_t)b * TS * 3072 + hd * 192);
  int srowK = lane >> 3;
  int sslotK = (lane & 7) ^ srowK;     // rule #21 pre-swizzled source slot
  constexpr float SCL = 0.18033688011f;  // 0.125 * log2(e)

  int q0 = T * 64 + qsub * 32;
  int nkt = T + 1;
  int qlim = qsub * 32 + ql;           // kv-local causal bound on tile T

  // Q fragments: lane holds Q[q0+ql][dh = ks*16 + 8*half + 0..7]
  const unsigned short* qrow = qkv_u + (size_t)(q0 + ql) * 3072;
  bf16x8 qf[4];
#pragma unroll
  for (int ks = 0; ks < 4; ++ks)
    qf[ks] = *(const bf16x8*)(qrow + ks * 16 + 8 * half);

  float m_st = -3.0e38f, l_own = 0.0f;
  f32x16 oaccT[2];
#pragma unroll
  for (int dt = 0; dt < 2; ++dt)
#pragma unroll
    for (int r = 0; r < 16; ++r) oaccT[dt][r] = 0.0f;

  uint32_t vr[16];                     // V staging regs

#define STAGE_K(KT, BUF)                                                      \
  {                                                                           \
    _Pragma("unroll")                                                         \
    for (int tt = 0; tt < 2; ++tt) {                                          \
      int chunk = w * 2 + tt;                                                 \
      int row = (KT) * 64 + chunk * 8 + srowK;                                \
      const char* g = (const char*)qkv_u + (size_t)row * 6144 + 128 +         \
                      sslotK * 16;                                            \
      gload16(g, sK0 + (BUF) * 8192 + chunk * 1024);                          \
    }                                                                         \
  }
#define LOAD_V(KT)                                                            \
  {                                                                           \
    _Pragma("unroll")                                                         \
    for (int p = 0; p < 16; ++p)                                              \
      vr[p] = qkv_u[(size_t)((KT) * 64 + w * 16 + p) * 3072 + 128 + lane];    \
  }
#define COMMIT_V(BUF)                                                         \
  {                                                                           \
    uint32_t wd[8];                                                           \
    _Pragma("unroll")                                                         \
    for (int e = 0; e < 8; ++e) wd[e] = vr[2 * e] | (vr[2 * e + 1] << 16);    \
    _Pragma("unroll")                                                         \
    for (int u = 0; u < 2; ++u) {                                             \
      uint4 q4;                                                               \
      q4.x = wd[4 * u]; q4.y = wd[4 * u + 1];                                 \
      q4.z = wd[4 * u + 2]; q4.w = wd[4 * u + 3];                             \
      int off = lane * 128 + ((w * 32 + u * 16) ^ ((lane & 7) << 4));         \
      *(uint4*)(sV0 + (BUF) * 8192 + off) = q4;                               \
    }                                                                         \
  }

  STAGE_K(0, 0);
  LOAD_V(0);
  COMMIT_V(0);
  __syncthreads();

  for (int kt = 0; kt < nkt; ++kt) {
    int cur = kt & 1;
    int nxt = cur ^ 1;
    if (kt + 1 < nkt) {                // issue-early (T14)
      STAGE_K(kt + 1, nxt);
      LOAD_V(kt + 1);
    }
    bool act = (kt < T) | (ntw <= qsub);
    if (act) {
      // ---- QK^T (swapped): sc = K-rows(ntw*32..+31) x Q ----
      f32x16 sc;
#pragma unroll
      for (int r = 0; r < 16; ++r) sc[r] = 0.0f;
#pragma unroll
      for (int ks = 0; ks < 4; ++ks) {
        int row = ntw * 32 + ql;
        int off = row * 128 + ((ks * 32 + 16 * half) ^ ((row & 7) << 4));
        bf16x8 kf = *(const bf16x8*)(sK0 + cur * 8192 + off);
        sc = __builtin_amdgcn_mfma_f32_32x32x16_bf16(kf, qf[ks], sc, 0, 0, 0);
      }
      // ---- scale (+mask only on the diagonal tile) ----
      if (kt == T) {
#pragma unroll
        for (int r = 0; r < 16; ++r) {
          int loc = ntw * 32 + (r & 3) + 8 * (r >> 2) + 4 * half;
          float s = sc[r] * SCL;
          sc[r] = (loc <= qlim) ? s : -3.0e38f;
        }
      } else {
#pragma unroll
        for (int r = 0; r < 16; ++r) sc[r] *= SCL;
      }
      // ---- tree max + one cross-half shfl ----
      float t8[8];
#pragma unroll
      for (int e = 0; e < 8; ++e) t8[e] = fmaxf(sc[e], sc[e + 8]);
#pragma unroll
      for (int e = 0; e < 4; ++e) t8[e] = fmaxf(t8[e], t8[e + 4]);
      float pm = fmaxf(fmaxf(t8[0], t8[2]), fmaxf(t8[1], t8[3]));
      pm = fmaxf(pm, __shfl_xor(pm, 32));
      // ---- T13 defer-rescale (11.5 = 8/ln2 headroom in log2 space) ----
      if (!__all(pm <= m_st + 11.5f)) {
        float mn = fmaxf(m_st, pm);
        float f = ex2(m_st - mn);
        l_own *= f;
#pragma unroll
        for (int dt = 0; dt < 2; ++dt)
#pragma unroll
          for (int r = 0; r < 16; ++r) oaccT[dt][r] *= f;
        m_st = mn;
      }
      // ---- exp2 + tree sum ----
#pragma unroll
      for (int r = 0; r < 16; ++r) sc[r] = ex2(sc[r] - m_st);
#pragma unroll
      for (int e = 0; e < 8; ++e) t8[e] = sc[e] + sc[e + 8];
#pragma unroll
      for (int e = 0; e < 4; ++e) t8[e] = t8[e] + t8[e + 4];
      l_own += (t8[0] + t8[2]) + (t8[1] + t8[3]);
      // ---- pack P to bf16 (cvt_pk) + cross-half word exchange ----
      uint32_t w8[8];
#pragma unroll
      for (int g = 0; g < 4; ++g)
#pragma unroll
        for (int e = 0; e < 2; ++e)
          w8[g * 2 + e] = cvtpk_bf16(sc[4 * g + 2 * e], sc[4 * g + 2 * e + 1]);
      uint32_t rcv[2][2];
#pragma unroll
      for (int s = 0; s < 2; ++s)
#pragma unroll
        for (int e = 0; e < 2; ++e) {
          uint32_t snd = half ? w8[4 * s + e] : w8[4 * s + 2 + e];
          rcv[s][e] = (uint32_t)__shfl_xor((int)snd, 32);
        }
      // ---- PV (swapped): oaccT[dt] += V^T x P^T ----
#pragma unroll
      for (int s = 0; s < 2; ++s) {
        union { uint32_t u[4]; bf16x8 v; } pf;
        if (half == 0) {
          pf.u[0] = w8[4 * s]; pf.u[1] = w8[4 * s + 1];
          pf.u[2] = rcv[s][0]; pf.u[3] = rcv[s][1];
        } else {
          pf.u[0] = rcv[s][0]; pf.u[1] = rcv[s][1];
          pf.u[2] = w8[4 * s + 2]; pf.u[3] = w8[4 * s + 3];
        }
#pragma unroll
        for (int dt = 0; dt < 2; ++dt) {
          int row = dt * 32 + ql;
          int off = row * 128 +
                    ((ntw * 64 + s * 32 + 16 * half) ^ ((row & 7) << 4));
          bf16x8 vtf = *(const bf16x8*)(sV0 + cur * 8192 + off);
          oaccT[dt] = __builtin_amdgcn_mfma_f32_32x32x16_bf16(vtf, pf.v, oaccT[dt], 0, 0, 0);
        }
      }
    }
    if (kt + 1 < nkt) COMMIT_V(nxt);   // write-late
    __syncthreads();
  }

  // ---- ntw-partner merge via LDS (K/V buffers dead now) ----
  float l_tot = l_own + __shfl_xor(l_own, 32);
  float* scr = (float*)smem;           // [idx 0..33][qsub 0..1][lane 0..63]
  if (ntw == 1) {
    scr[(0 * 2 + qsub) * 64 + lane] = m_st;
    scr[(1 * 2 + qsub) * 64 + lane] = l_tot;
#pragma unroll
    for (int dt = 0; dt < 2; ++dt)
#pragma unroll
      for (int r = 0; r < 16; ++r)
        scr[((2 + dt * 16 + r) * 2 + qsub) * 64 + lane] = oaccT[dt][r];
  }
  __syncthreads();
  if (ntw == 0) {
    float mB = scr[(0 * 2 + qsub) * 64 + lane];
    float lB = scr[(1 * 2 + qsub) * 64 + lane];
    float m = fmaxf(m_st, mB);
    float wa = ex2(m_st - m), wb = ex2(mB - m);
    float linv = 1.0f / (l_tot * wa + lB * wb);
    int qg = q0 + ql;
    bf16* orow = outp + (size_t)(b * TS + qg) * TD + hd * 64;
#pragma unroll
    for (int dt = 0; dt < 2; ++dt)
#pragma unroll
      for (int g = 0; g < 4; ++g) {
        ushort4 s4;
        float o0, o1, o2, o3;
        o0 = (oaccT[dt][4 * g] * wa +
              scr[((2 + dt * 16 + 4 * g) * 2 + qsub) * 64 + lane] * wb) * linv;
        o1 = (oaccT[dt][4 * g + 1] * wa +
              scr[((2 + dt * 16 + 4 * g + 1) * 2 + qsub) * 64 + lane] * wb) * linv;
        o2 = (oaccT[dt][4 * g + 2] * wa +
              scr[((2 + dt * 16 + 4 * g + 2) * 2 + qsub) * 64 + lane] * wb) * linv;
        o3 = (oaccT[dt][4 * g + 3] * wa +
              scr[((2 + dt * 16 + 4 * g + 3) * 2 + qsub) * 64 + lane] * wb) * linv;
        s4.x = f2bfbits(o0); s4.y = f2bfbits(o1);
        s4.z = f2bfbits(o2); s4.w = f2bfbits(o3);
        *(ushort4*)(orow + dt * 32 + 8 * g + 4 * half) = s4;
      }
  }
#undef STAGE_K
#undef LOAD_V
#undef COMMIT_V
}

// ---------------- launch -----------------------------------------------------
extern "C" void kernel_launch(void* const* d_in, const int* in_sizes, int n_in,
                              void* d_out, int out_size, void* d_ws, size_t ws_size,
                              hipStream_t stream) {
  const float* x      = (const float*)d_in[0];
  const float* gamma1 = (const float*)d_in[1];
  const float* beta1  = (const float*)d_in[2];
  const float* W_qkv  = (const float*)d_in[3];
  const float* b_qkv  = (const float*)d_in[4];
  const float* W_o    = (const float*)d_in[5];
  const float* b_o    = (const float*)d_in[6];
  const float* gamma2 = (const float*)d_in[7];
  const float* beta2  = (const float*)d_in[8];
  const float* W_up   = (const float*)d_in[9];
  const float* b_up   = (const float*)d_in[10];
  const float* W_down = (const float*)d_in[11];
  const float* b_down = (const float*)d_in[12];

  char* ws = (char*)d_ws;
  bf16*  wt_qkv  = (bf16*)(ws + 0);                  //  6291456
  bf16*  wt_o    = (bf16*)(ws + 6291456);            //  2097152
  bf16*  wt_up   = (bf16*)(ws + 8388608);            //  8388608
  bf16*  wt_down = (bf16*)(ws + 16777216);           //  8388608
  bf16*  h1      = (bf16*)(ws + 25165824);           //  8388608
  bf16*  qkvb    = (bf16*)(ws + 33554432);           // 25165824
  bf16*  ob      = (bf16*)(ws + 58720256);           //  8388608
  float* attn_o  = (float*)(ws + 67108864);          // 16777216
  bf16*  h2      = (bf16*)(ws + 83886080);           //  8388608
  bf16*  ub      = (bf16*)(ws + 92274688);           // 33554432
  float* outf    = (float*)d_out;

  k_transpose_bf16<<<dim3(16, 48), 256, 0, stream>>>(W_qkv, wt_qkv, 1024, 3072);
  k_transpose_bf16<<<dim3(16, 16), 256, 0, stream>>>(W_o, wt_o, 1024, 1024);
  k_transpose_bf16<<<dim3(16, 64), 256, 0, stream>>>(W_up, wt_up, 1024, 4096);
  k_transpose_bf16<<<dim3(64, 16), 256, 0, stream>>>(W_down, wt_down, 4096, 1024);

  k_layernorm<<<TM, 256, 0, stream>>>(x, gamma1, beta1, h1);
  // QKV: 4096x3072 @ K=1024, 128x128 tiles -> 768 blocks
  k_gemm<0, 128><<<768, 256, 0, stream>>>(h1, wt_qkv, b_qkv, nullptr, qkvb, 3072, 1024);
  k_attn<<<dim3(32, 32), 256, 0, stream>>>(qkvb, ob);
  // O-proj: 4096x1024 @ K=1024, 64x128 tiles -> 512 blocks (2/CU)
  k_gemm<1, 64><<<512, 256, 0, stream>>>(ob, wt_o, b_o, x, attn_o, 1024, 1024);
  k_layernorm<<<TM, 256, 0, stream>>>(attn_o, gamma2, beta2, h2);
  // Up: 4096x4096 @ K=1024, 128x128 tiles -> 1024 blocks
  k_gemm<2, 128><<<1024, 256, 0, stream>>>(h2, wt_up, b_up, nullptr, ub, 4096, 1024);
  // Down: 4096x1024 @ K=4096, 64x128 tiles -> 512 blocks (2/CU)
  k_gemm<1, 64><<<512, 256, 0, stream>>>(ub, wt_down, b_down, attn_o, outf, 1024, 4096);
}